// Round 4
// baseline (203.468 us; speedup 1.0000x reference)
//
#include <hip/hip_runtime.h>

// B=2, L=2048, D=1024, H=16, HD=64. fp32 I/O (confirmed R1-R3), bf16 internals.
// Fast path (ws >= 32MB):
//   convert: x->xbf (d_out lo 8MB), {WQ,WK,WV,Wc}->wbf (ws[0:8MB))
//   fused QKV gemm128 (z=3, global_load_lds staging): Q->d_out hi 8MB [bh][l][hd],
//       K->ws[8:16) [bh][l][hd], VT->ws[16:24) [bh][hd][l]
//   attn32p: swapped-QK 32x32 MFMA flash attention (R2-proven math) with
//       PAIR-BAND scheduling (R0-proven pattern): block owns bands A and 15-A,
//       both computed in ONE k-tile pass (shared K/V staging; lo-band active
//       while s <= its diag). Uniform 32/34 wave-steps per block -> no residency
//       decay (R2's 11.6% occupancy fix). In-register softmax (exp2 domain,
//       no-max), P->A-frag via v_cvt_pk_bf16_f32 + v_permlane32_swap_b32.
//       512 blocks, 2/CU; pairs (A,7-A) co-reside to balance staging length.
//       -> mixed ws[24:32) [4096][1024] bf16
//   gemm128 (z=1): y = mixed @ Wc^T -> d_out fp32
// Fallback (ws < 32MB): round-3 proven path (probe + per-batch, 12MB).

typedef __bf16 bf16x8 __attribute__((ext_vector_type(8)));
typedef float f32x4 __attribute__((ext_vector_type(4)));
typedef float f32x16 __attribute__((ext_vector_type(16)));
typedef unsigned short us4 __attribute__((ext_vector_type(4)));

#if defined(__has_builtin)
#if __has_builtin(__builtin_amdgcn_global_load_lds)
#define HAS_GLL 1
#endif
#if __has_builtin(__builtin_amdgcn_exp2f)
#define EXP2F(x) __builtin_amdgcn_exp2f(x)
#endif
#endif
#ifndef HAS_GLL
#define HAS_GLL 0
#endif
#ifndef EXP2F
#define EXP2F(x) exp2f(x)
#endif

__device__ __forceinline__ float bf2f(unsigned short u) {
    union { unsigned int i; float f; } v; v.i = ((unsigned int)u) << 16; return v.f;
}
__device__ __forceinline__ unsigned short f2bf(float f) {
    union { float f; unsigned int i; } v; v.f = f;
    unsigned int r = v.i + 0x7FFFu + ((v.i >> 16) & 1u);
    return (unsigned short)(r >> 16);
}
__device__ __forceinline__ f32x4 mfma16(bf16x8 a, bf16x8 b, f32x4 c) {
    return __builtin_amdgcn_mfma_f32_16x16x32_bf16(a, b, c, 0, 0, 0);
}
__device__ __forceinline__ f32x16 mfma32(bf16x8 a, bf16x8 b, f32x16 c) {
    return __builtin_amdgcn_mfma_f32_32x32x16_bf16(a, b, c, 0, 0, 0);
}
__device__ __forceinline__ float clamp4(float v) {
    return fminf(fmaxf(v, -1e4f), 1e4f);
}
union U8 { unsigned short s[8]; bf16x8 v; };

// two f32 -> packed bf16 pair (RNE); no builtin on gfx950 (m240)
__device__ __forceinline__ unsigned int cvt_pk_bf16(float lo, float hi) {
    unsigned int r;
    asm("v_cvt_pk_bf16_f32 %0, %1, %2" : "=v"(r) : "v"(lo), "v"(hi));
    return r;
}
// exchange a.hi32lanes <-> b.lo32lanes (gfx950 cross-half lane swap)
__device__ __forceinline__ void pl32swap(unsigned int& a, unsigned int& b) {
    asm volatile("v_permlane32_swap_b32 %0, %1" : "+v"(a), "+v"(b));
}

#if HAS_GLL
// async global->LDS, 16B/lane. lds ptr must be wave-uniform; HW scatters lane i
// to lds + i*16 (m104: no per-lane LDS scatter, keep dest contiguous).
__device__ __forceinline__ void gl_lds16(const unsigned short* g, unsigned short* l) {
    __builtin_amdgcn_global_load_lds(
        (const __attribute__((address_space(1))) void*)g,
        (__attribute__((address_space(3))) void*)l, 16, 0, 0);
}
#endif

// ------------------------- fast path kernels -------------------------

// 8M elems: [0,4M) x -> xbf; [4M,8M) weights sel=(j>>20) -> wbf+sel*1M.
__global__ __launch_bounds__(256) void convert_all(
    const float* __restrict__ x, const float* __restrict__ WQ,
    const float* __restrict__ WK, const float* __restrict__ WV,
    const float* __restrict__ Wc,
    unsigned short* __restrict__ xbf, unsigned short* __restrict__ wbf)
{
    size_t e = ((size_t)blockIdx.x * 256 + threadIdx.x) * 8;
    const float* src; unsigned short* dst; size_t off;
    if (e < 4194304) { src = x; dst = xbf; off = e; }
    else {
        size_t j = e - 4194304; int sel = (int)(j >> 20); off = j & 1048575;
        src = (sel == 0) ? WQ : (sel == 1) ? WK : (sel == 2) ? WV : Wc;
        dst = wbf + (size_t)sel * 1048576;
    }
    f32x4 a = *(const f32x4*)(src + off);
    f32x4 b = *(const f32x4*)(src + off + 4);
    U8 u;
    u.s[0] = f2bf(a[0]); u.s[1] = f2bf(a[1]); u.s[2] = f2bf(a[2]); u.s[3] = f2bf(a[3]);
    u.s[4] = f2bf(b[0]); u.s[5] = f2bf(b[1]); u.s[6] = f2bf(b[2]); u.s[7] = f2bf(b[3]);
    *(bf16x8*)(dst + off) = u.v;
}

// 128x128 tile, BK=32, 4 waves 2x2, each wave 64x64 (4x4 16x16x32 frags).
// Staging via global_load_lds width=16 (m97 ladder step).
// mode 0: Q -> [bh][l][hd]  mode 1: K -> same  mode 2: VT -> [bh][hd][l]
// mode 3: y -> fp32 [m][n]
__global__ __launch_bounds__(256) void gemm128(
    const unsigned short* __restrict__ A, const unsigned short* __restrict__ Wbase,
    const float* __restrict__ b0, const float* __restrict__ b1, const float* __restrict__ b2,
    void* __restrict__ d0, void* __restrict__ d1, void* __restrict__ d2, int modeBase)
{
    const int z = blockIdx.z;
    const unsigned short* W = Wbase + (size_t)z * 1048576;
    const float* bias = (z == 0) ? b0 : (z == 1) ? b1 : b2;
    void* dst = (z == 0) ? d0 : (z == 1) ? d1 : d2;
    const int mode = modeBase + z;

    __shared__ __align__(16) unsigned short At[128][32];
    __shared__ __align__(16) unsigned short Bt[128][32];

    const int mb = blockIdx.y * 128, nb = blockIdx.x * 128;
    const int tid = threadIdx.x, w = tid >> 6, lane = tid & 63;
    const int wr = w >> 1, wc = w & 1;
    const int col = lane & 15, quad = lane >> 4;

    f32x4 acc[4][4];
    for (int i = 0; i < 4; ++i) for (int j = 0; j < 4; ++j) acc[i][j] = (f32x4){0.f, 0.f, 0.f, 0.f};

#if HAS_GLL
    // wave w stages rows [w*32, w*32+32): lane l -> row w*32 + l/4, chunk (l&3)*8
    const unsigned short* ga = A + (size_t)(mb + w * 32 + (lane >> 2)) * 1024 + (lane & 3) * 8;
    const unsigned short* gw = W + (size_t)(nb + w * 32 + (lane >> 2)) * 1024 + (lane & 3) * 8;
    unsigned short* lA0 = &At[w * 32][0];        // wave-uniform bases
    unsigned short* lA1 = &At[w * 32 + 16][0];
    unsigned short* lB0 = &Bt[w * 32][0];
    unsigned short* lB1 = &Bt[w * 32 + 16][0];
#else
    const int srow = w * 32 + (lane >> 1);
    const int scol = (lane & 1) * 16;
    const unsigned short* Ab = A + (size_t)(mb + srow) * 1024 + scol;
    const unsigned short* Wb = W + (size_t)(nb + srow) * 1024 + scol;
#endif

    for (int kb = 0; kb < 1024; kb += 32) {
#if HAS_GLL
        gl_lds16(ga + kb, lA0);
        gl_lds16(ga + kb + 16 * 1024, lA1);
        gl_lds16(gw + kb, lB0);
        gl_lds16(gw + kb + 16 * 1024, lB1);
#else
        *(bf16x8*)&At[srow][scol]     = *(const bf16x8*)(Ab + kb);
        *(bf16x8*)&At[srow][scol + 8] = *(const bf16x8*)(Ab + kb + 8);
        *(bf16x8*)&Bt[srow][scol]     = *(const bf16x8*)(Wb + kb);
        *(bf16x8*)&Bt[srow][scol + 8] = *(const bf16x8*)(Wb + kb + 8);
#endif
        __syncthreads();
        bf16x8 a[4], b[4];
        for (int i = 0; i < 4; ++i) a[i] = *(const bf16x8*)&At[wr * 64 + i * 16 + col][quad * 8];
        for (int j = 0; j < 4; ++j) b[j] = *(const bf16x8*)&Bt[wc * 64 + j * 16 + col][quad * 8];
        for (int i = 0; i < 4; ++i)
            for (int j = 0; j < 4; ++j)
                acc[i][j] = mfma16(a[i], b[j], acc[i][j]);
        __syncthreads();
    }

    for (int i = 0; i < 4; ++i) {
        const int mbase = mb + wr * 64 + i * 16 + quad * 4;
        const int bb = mbase >> 11, l = mbase & 2047;
        for (int j = 0; j < 4; ++j) {
            const int n = nb + wc * 64 + j * 16 + col;
            const float bv = bias ? bias[n] : 0.f;
            if (mode == 3) {
                float* o = (float*)dst;
                for (int r = 0; r < 4; ++r)
                    o[(size_t)(mbase + r) * 1024 + n] = clamp4(acc[i][j][r] + bv);
            } else if (mode == 2) {
                const int h = n >> 6, hd = n & 63;
                us4 pk;
                for (int r = 0; r < 4; ++r) pk[r] = f2bf(clamp4(acc[i][j][r] + bv));
                *(us4*)((unsigned short*)dst + (size_t)(bb * 16 + h) * 131072
                        + (size_t)hd * 2048 + l) = pk;
            } else {
                const int h = n >> 6, hd = n & 63;
                unsigned short* o = (unsigned short*)dst + (size_t)(bb * 16 + h) * 131072
                                    + (size_t)l * 64 + hd;
                for (int r = 0; r < 4; ++r)
                    o[(size_t)r * 64] = f2bf(clamp4(acc[i][j][r] + bv));
            }
        }
    }
}

// ---- attn32p: swapped-QK 32x32 in-register-softmax flash attention ----
// S^T acc layout (m74/m101): col q = lane&31; k = (reg&3) + 8*(reg>>2) + 4*hi.
// A-frag build (m214 recipe): pairs (r,r+1) cvt_pk'd, (r0..) swapped with (r4..)
// via v_permlane32_swap: first -> [lo,lo] word, second -> [hi,hi] word.
// (soft_pack / attn32_step are verbatim the R2-passing code.)

template<bool DIAG>
__device__ __forceinline__ void soft_pack(
    const f32x16& sacc, bf16x8* pa, float& lpart, int kg0, int qg)
{
    float p[16];
#pragma unroll
    for (int r = 0; r < 16; ++r) {
        float v = sacc[r] * 0.18033688f;   // 0.125 * log2(e): exp2 domain
        if (DIAG) {
            int kg = kg0 + (r & 3) + 8 * (r >> 2);
            if (kg > qg) v = -1e30f;
        }
        v = fminf(v, 86.5f);               // overflow guard (== e-domain 60)
        p[r] = EXP2F(v);
    }
    float t0 = (p[0] + p[1]) + (p[2] + p[3]);
    float t1 = (p[4] + p[5]) + (p[6] + p[7]);
    float t2 = (p[8] + p[9]) + (p[10] + p[11]);
    float t3 = (p[12] + p[13]) + (p[14] + p[15]);
    lpart += (t0 + t1) + (t2 + t3);
#pragma unroll
    for (int c = 0; c < 2; ++c) {
        unsigned int a0 = cvt_pk_bf16(p[8*c + 0], p[8*c + 1]);
        unsigned int b0 = cvt_pk_bf16(p[8*c + 4], p[8*c + 5]);
        unsigned int a1 = cvt_pk_bf16(p[8*c + 2], p[8*c + 3]);
        unsigned int b1 = cvt_pk_bf16(p[8*c + 6], p[8*c + 7]);
        pl32swap(a0, b0);                  // a0 -> w0 (lo:k01 / hi:k89), b0 -> w2
        pl32swap(a1, b1);                  // a1 -> w1,                  b1 -> w3
        union PW { unsigned int w[4]; bf16x8 v; } pw;
        pw.w[0] = a0; pw.w[1] = a1; pw.w[2] = b0; pw.w[3] = b1;
        pa[c] = pw.v;
    }
}

template<bool DIAG>
__device__ __forceinline__ void attn32_step(
    const unsigned short (*__restrict__ Kt)[72], const unsigned short (*__restrict__ Vt)[72],
    const bf16x8* __restrict__ qf, f32x16* __restrict__ oacc, float& lpart,
    int kb, int qg, int hi, int c31)
{
    f32x16 s0, s1;
#pragma unroll
    for (int r = 0; r < 16; ++r) { s0[r] = 0.f; s1[r] = 0.f; }
#pragma unroll
    for (int dc = 0; dc < 4; ++dc) {
        bf16x8 kf0 = *(const bf16x8*)&Kt[c31][dc * 16 + hi * 8];
        bf16x8 kf1 = *(const bf16x8*)&Kt[32 + c31][dc * 16 + hi * 8];
        s0 = mfma32(kf0, qf[dc], s0);
        s1 = mfma32(kf1, qf[dc], s1);
    }
    bf16x8 pa[4];
    soft_pack<DIAG>(s0, pa,     lpart, kb + 4 * hi,      qg);
    soft_pack<DIAG>(s1, pa + 2, lpart, kb + 32 + 4 * hi, qg);
#pragma unroll
    for (int b2 = 0; b2 < 2; ++b2)
#pragma unroll
        for (int kc = 0; kc < 4; ++kc) {
            bf16x8 vf = *(const bf16x8*)&Vt[b2 * 32 + c31][kc * 16 + hi * 8];
            oacc[b2] = mfma32(pa[kc], vf, oacc[b2]);
        }
}

__device__ __forceinline__ void attn_write32(
    unsigned short* __restrict__ mixed, int gb, int h, int q0, int c31, int hi,
    const f32x16* __restrict__ oacc, const float* __restrict__ lrow)
{
    f32x4 iv[4];
#pragma unroll
    for (int m = 0; m < 4; ++m) {
        f32x4 lv = *(const f32x4*)&lrow[4 * hi + 8 * m];
#pragma unroll
        for (int r = 0; r < 4; ++r) iv[m][r] = 1.f / lv[r];
    }
#pragma unroll
    for (int b2 = 0; b2 < 2; ++b2)
#pragma unroll
        for (int r = 0; r < 16; ++r) {
            const int qrow = q0 + 4 * hi + (r & 3) + 8 * (r >> 2);
            const float val = clamp4(oacc[b2][r] * iv[r >> 2][r & 3]);
            mixed[(size_t)(gb * 2048 + qrow) * 1024 + h * 64 + b2 * 32 + c31] = f2bf(val);
        }
}

// Block = 4 waves, owns TWO 128-row bands: A and 15-A. One pass over k-tiles
// 0..(31-2A): per tile, every wave computes its hi-band chunk (until its diag =
// last needed tile) and its lo-band chunk while s <= diag_lo. Per-wave work =
// 32 (w<2) / 34 (w>=2) tile-steps, uniform over all blocks -> no residency
// decay. Staging length 32-2A varies; CU-pairs (A,7-A) via stride-256 balance.
// Grid 512 = {j-pair sel, bh}: i=lb&255, kk=lb>>8; bh=i&31; j=i>>5; A=kk?7-j:j.
// Q,K: [bh][l][hd]; V: [bh][hd][l]; mixed: [4096][1024] bf16.
__global__ __launch_bounds__(256, 2) void attn32p(
    const unsigned short* __restrict__ Q, const unsigned short* __restrict__ K,
    const unsigned short* __restrict__ V, unsigned short* __restrict__ mixed)
{
    const int lb = blockIdx.x;
    const int i = lb & 255, kk = lb >> 8;
    const int bh = i & 31, j = i >> 5;        // j in [0,8)
    const int A = kk ? (7 - j) : j;           // lo band index in [0,8)
    const int ntiles = 32 - 2 * A;            // staged k-tiles

    const int tid = threadIdx.x, w = tid >> 6, lane = tid & 63;
    const int c31 = lane & 31, hi = lane >> 5;

    __shared__ __align__(16) unsigned short Kt[64][72];
    __shared__ __align__(16) unsigned short Vt[64][72];
    __shared__ __align__(16) float lslab[4][64];

    const unsigned short* Qb = Q + (size_t)bh * 131072;
    const unsigned short* Kb = K + (size_t)bh * 131072;
    const unsigned short* Vb = V + (size_t)bh * 131072;

    const int qlo0 = A * 128 + w * 32;        // lo-band wave chunk
    const int qhi0 = (15 - A) * 128 + w * 32; // hi-band wave chunk
    const int qglo = qlo0 + c31, qghi = qhi0 + c31;
    const int slo = 2 * A + (w >> 1);         // lo diag tile
    const int shi = 30 - 2 * A + (w >> 1);    // hi diag tile (<= ntiles-1)

    bf16x8 qflo[4], qfhi[4];
    {
        const unsigned short* Qr = Qb + (size_t)qglo * 64 + hi * 8;
        const unsigned short* Qs = Qb + (size_t)qghi * 64 + hi * 8;
#pragma unroll
        for (int dc = 0; dc < 4; ++dc) {
            qflo[dc] = *(const bf16x8*)(Qr + dc * 16);
            qfhi[dc] = *(const bf16x8*)(Qs + dc * 16);
        }
    }

    f32x16 olo[2], ohi[2];
#pragma unroll
    for (int b2 = 0; b2 < 2; ++b2)
#pragma unroll
        for (int r = 0; r < 16; ++r) { olo[b2][r] = 0.f; ohi[b2][r] = 0.f; }
    float lplo = 0.f, lphi = 0.f;

    const int sr = tid >> 3, sc = (tid & 7) * 8;

    // prefetch k-tile 0 (R2-proven staging pattern)
    const unsigned short* kp = Kb + (size_t)sr * 64 + sc;
    const unsigned short* vp = Vb + (size_t)sr * 2048 + sc;
    bf16x8 pk0 = *(const bf16x8*)kp, pk1 = *(const bf16x8*)(kp + 32 * 64);
    bf16x8 pv0 = *(const bf16x8*)vp, pv1 = *(const bf16x8*)(vp + 32 * 2048);

    for (int s = 0; s < ntiles; ++s) {
        __syncthreads();                     // prior iter's LDS reads complete
        *(bf16x8*)&Kt[sr][sc]      = pk0;
        *(bf16x8*)&Kt[sr + 32][sc] = pk1;
        *(bf16x8*)&Vt[sr][sc]      = pv0;
        *(bf16x8*)&Vt[sr + 32][sc] = pv1;
        __syncthreads();
        if (s + 1 < ntiles) {                // issue next tile's loads now:
            const int kb2 = (s + 1) * 64;    // latency overlaps this iter's compute
            const unsigned short* kp2 = Kb + (size_t)(kb2 + sr) * 64 + sc;
            const unsigned short* vp2 = Vb + (size_t)sr * 2048 + kb2 + sc;
            pk0 = *(const bf16x8*)kp2; pk1 = *(const bf16x8*)(kp2 + 32 * 64);
            pv0 = *(const bf16x8*)vp2; pv1 = *(const bf16x8*)(vp2 + 32 * 2048);
        }
        // hi band: live until its diag (last or second-to-last staged tile)
        if (s < shi)
            attn32_step<false>(Kt, Vt, qfhi, ohi, lphi, s * 64, qghi, hi, c31);
        else if (s == shi)
            attn32_step<true >(Kt, Vt, qfhi, ohi, lphi, s * 64, qghi, hi, c31);
        // lo band: live while s <= slo (slo <= ntiles-1 always since A<8)
        if (s < slo)
            attn32_step<false>(Kt, Vt, qflo, olo, lplo, s * 64, qglo, hi, c31);
        else if (s == slo)
            attn32_step<true >(Kt, Vt, qflo, olo, lplo, s * 64, qglo, hi, c31);
    }

    // row-sums: combine lane-half partials; per-wave slab, intra-wave ordered
    float tlo = lplo + __shfl_xor(lplo, 32, 64);
    float thi = lphi + __shfl_xor(lphi, 32, 64);
    if (lane < 32) { lslab[w][lane] = tlo; lslab[w][32 + lane] = thi; }

    const int gb = bh >> 4, h = bh & 15;
    attn_write32(mixed, gb, h, qlo0, c31, hi, olo, &lslab[w][0]);
    attn_write32(mixed, gb, h, qhi0, c31, hi, ohi, &lslab[w][32]);
}

// ------------------------- fallback (round-3 proven) -------------------------

__device__ __forceinline__ bf16x8 load8(const void* base, size_t eoff, int asF32) {
    if (asF32) {
        const float* p = (const float*)base + eoff;
        f32x4 a = *(const f32x4*)p;
        f32x4 b = *(const f32x4*)(p + 4);
        U8 u;
        u.s[0]=f2bf(a[0]); u.s[1]=f2bf(a[1]); u.s[2]=f2bf(a[2]); u.s[3]=f2bf(a[3]);
        u.s[4]=f2bf(b[0]); u.s[5]=f2bf(b[1]); u.s[6]=f2bf(b[2]); u.s[7]=f2bf(b[3]);
        return u.v;
    }
    return *(const bf16x8*)((const unsigned short*)base + eoff);
}

__global__ void dtype_probe(const unsigned short* __restrict__ x, int* __restrict__ flag) {
    if (threadIdx.x == 0) {
        int c = 0;
        for (int i = 0; i < 128; ++i) {
            int e = (x[2 * i] >> 7) & 0xFF;
            if (e >= 100 && e <= 135) ++c;
        }
        *flag = (c < 64) ? 1 : 0;
    }
}

__global__ __launch_bounds__(256) void gemm_bt(
    const void* __restrict__ Ap, const void* __restrict__ Wp,
    const void* __restrict__ biasp, void* __restrict__ dout,
    unsigned short* __restrict__ wsdst, const int* __restrict__ flag,
    long aOff, long outOff, int mode, int aFlagged)
{
    const int f32 = *flag;
    __shared__ __align__(16) unsigned short At[64][32];
    __shared__ __align__(16) unsigned short Bt[64][32];
    const int mb = blockIdx.y * 64, nb = blockIdx.x * 64;
    const int tid = threadIdx.x;
    const int w = tid >> 6, lane = tid & 63;
    const int wr = w >> 1, wc = w & 1;
    const int col = lane & 15, quad = lane >> 4;
    const int srow = tid >> 2, schunk = (tid & 3) * 8;
    const int aF = aFlagged && f32;

    f32x4 acc[2][2];
    for (int i = 0; i < 2; ++i) for (int j = 0; j < 2; ++j) acc[i][j] = (f32x4){0.f,0.f,0.f,0.f};

    const size_t aBase = (size_t)aOff + (size_t)(mb + srow) * 1024 + schunk;
    const size_t wBase = (size_t)(nb + srow) * 1024 + schunk;

    for (int kb = 0; kb < 1024; kb += 32) {
        *(bf16x8*)(&At[srow][schunk]) = load8(Ap, aBase + kb, aF);
        *(bf16x8*)(&Bt[srow][schunk]) = load8(Wp, wBase + kb, f32);
        __syncthreads();
        bf16x8 a0 = *(const bf16x8*)(&At[wr * 32 + col][quad * 8]);
        bf16x8 a1 = *(const bf16x8*)(&At[wr * 32 + 16 + col][quad * 8]);
        bf16x8 b0 = *(const bf16x8*)(&Bt[wc * 32 + col][quad * 8]);
        bf16x8 b1 = *(const bf16x8*)(&Bt[wc * 32 + 16 + col][quad * 8]);
        acc[0][0] = mfma16(a0, b0, acc[0][0]);
        acc[0][1] = mfma16(a0, b1, acc[0][1]);
        acc[1][0] = mfma16(a1, b0, acc[1][0]);
        acc[1][1] = mfma16(a1, b1, acc[1][1]);
        __syncthreads();
    }

    for (int mi = 0; mi < 2; ++mi) {
        for (int ni = 0; ni < 2; ++ni) {
            int n = nb + wc * 32 + ni * 16 + col;
            float bv = 0.f;
            if (biasp) bv = f32 ? ((const float*)biasp)[n] : bf2f(((const unsigned short*)biasp)[n]);
            for (int r = 0; r < 4; ++r) {
                int m = mb + wr * 32 + mi * 16 + quad * 4 + r;
                float v = clamp4(acc[mi][ni][r] + bv);
                if (mode == 3) {
                    size_t idx = (size_t)outOff + (size_t)m * 1024 + n;
                    if (f32) ((float*)dout)[idx] = v;
                    else     ((unsigned short*)dout)[idx] = f2bf(v);
                } else {
                    int h = n >> 6, hd = n & 63;
                    size_t idx = (mode == 2)
                        ? (size_t)h * 131072 + (size_t)hd * 2048 + m
                        : (size_t)h * 131072 + (size_t)m * 64 + hd;
                    unsigned short* dstp = (mode == 0)
                        ? (unsigned short*)dout + (f32 ? 4194304 : 2097152)
                        : wsdst;
                    dstp[idx] = f2bf(v);
                }
            }
        }
    }
}

__global__ __launch_bounds__(256) void attn_kernel(
    const void* __restrict__ dout, const unsigned short* __restrict__ Kw,
    const unsigned short* __restrict__ Vw, unsigned short* __restrict__ mixed,
    const int* __restrict__ flag)
{
    const int f32 = *flag;
    const int qtile = blockIdx.x;
    const int h = blockIdx.y;
    const int w = threadIdx.x >> 6, lane = threadIdx.x & 63;
    const int col = lane & 15, quad = lane >> 4;

    __shared__ __align__(16) unsigned short Plds[4][16][64];

    const unsigned short* Qs = (const unsigned short*)dout + (f32 ? 4194304 : 2097152);
    const unsigned short* Qb = Qs + (size_t)h * 131072;
    const unsigned short* Kb = Kw + (size_t)h * 131072;
    const unsigned short* Vb = Vw + (size_t)h * 131072;

    const int q0 = qtile * 64 + w * 16;
    bf16x8 aq0 = *(const bf16x8*)(Qb + (size_t)(q0 + col) * 64 + quad * 8);
    bf16x8 aq1 = *(const bf16x8*)(Qb + (size_t)(q0 + col) * 64 + 32 + quad * 8);

    float m_run[4] = {-1e30f, -1e30f, -1e30f, -1e30f};
    float l_run[4] = {0.f, 0.f, 0.f, 0.f};
    f32x4 oacc[4];
    for (int i = 0; i < 4; ++i) oacc[i] = (f32x4){0.f, 0.f, 0.f, 0.f};

    for (int kt = 0; kt <= qtile; ++kt) {
        const int kb = kt * 64;
        f32x4 s[4];
        for (int t = 0; t < 4; ++t) {
            s[t] = (f32x4){0.f, 0.f, 0.f, 0.f};
            bf16x8 bk0 = *(const bf16x8*)(Kb + (size_t)(kb + t * 16 + col) * 64 + quad * 8);
            bf16x8 bk1 = *(const bf16x8*)(Kb + (size_t)(kb + t * 16 + col) * 64 + 32 + quad * 8);
            s[t] = mfma16(aq0, bk0, s[t]);
            s[t] = mfma16(aq1, bk1, s[t]);
        }
        for (int t = 0; t < 4; ++t)
            for (int r = 0; r < 4; ++r) {
                float v = clamp4(s[t][r] * 0.125f);
                if (kt == qtile && (t * 16 + col > w * 16 + quad * 4 + r)) v = -1e30f;
                s[t][r] = v;
            }
        float mt[4];
        for (int r = 0; r < 4; ++r)
            mt[r] = fmaxf(fmaxf(s[0][r], s[1][r]), fmaxf(s[2][r], s[3][r]));
        for (int off = 1; off < 16; off <<= 1)
            for (int r = 0; r < 4; ++r)
                mt[r] = fmaxf(mt[r], __shfl_xor(mt[r], off, 64));
        float alpha[4], rs[4], p[4][4];
        for (int r = 0; r < 4; ++r) {
            float mn = fmaxf(m_run[r], mt[r]);
            alpha[r] = __expf(m_run[r] - mn);
            m_run[r] = mn;
        }
        for (int t = 0; t < 4; ++t)
            for (int r = 0; r < 4; ++r)
                p[t][r] = __expf(s[t][r] - m_run[r]);
        for (int r = 0; r < 4; ++r)
            rs[r] = (p[0][r] + p[1][r]) + (p[2][r] + p[3][r]);
        for (int off = 1; off < 16; off <<= 1)
            for (int r = 0; r < 4; ++r)
                rs[r] += __shfl_xor(rs[r], off, 64);
        for (int r = 0; r < 4; ++r)
            l_run[r] = l_run[r] * alpha[r] + rs[r];
        for (int nt = 0; nt < 4; ++nt)
            for (int r = 0; r < 4; ++r)
                oacc[nt][r] *= alpha[r];
        for (int t = 0; t < 4; ++t)
            for (int r = 0; r < 4; ++r)
                Plds[w][quad * 4 + r][t * 16 + col] = f2bf(p[t][r]);
        __syncthreads();
        bf16x8 ap0 = *(const bf16x8*)(&Plds[w][col][quad * 8]);
        bf16x8 ap1 = *(const bf16x8*)(&Plds[w][col][32 + quad * 8]);
        for (int nt = 0; nt < 4; ++nt) {
            bf16x8 bv0 = *(const bf16x8*)(Vb + (size_t)(nt * 16 + col) * 2048 + kb + quad * 8);
            bf16x8 bv1 = *(const bf16x8*)(Vb + (size_t)(nt * 16 + col) * 2048 + kb + 32 + quad * 8);
            oacc[nt] = mfma16(ap0, bv0, oacc[nt]);
            oacc[nt] = mfma16(ap1, bv1, oacc[nt]);
        }
        __syncthreads();
    }

    float inv[4];
    for (int r = 0; r < 4; ++r) inv[r] = 1.f / l_run[r];
    for (int nt = 0; nt < 4; ++nt)
        for (int r = 0; r < 4; ++r) {
            int qrow = q0 + quad * 4 + r;
            mixed[(size_t)qrow * 1024 + h * 64 + nt * 16 + col] = f2bf(clamp4(oacc[nt][r] * inv[r]));
        }
}

// ------------------------- launcher -------------------------

extern "C" void kernel_launch(void* const* d_in, const int* in_sizes, int n_in,
                              void* d_out, int out_size, void* d_ws, size_t ws_size,
                              hipStream_t stream) {
    (void)in_sizes; (void)n_in; (void)out_size;
    const void* x  = d_in[0];
    const void* WQ = d_in[1]; const void* bQ = d_in[2];
    const void* WK = d_in[3]; const void* bK = d_in[4];
    const void* WV = d_in[5]; const void* bV = d_in[6];
    const void* Wc = d_in[7];

    if (ws_size >= (size_t)32 * 1024 * 1024) {
        unsigned short* wbf   = (unsigned short*)d_ws;      // 4M elems (8MB)
        unsigned short* Kst   = wbf + 4194304;
        unsigned short* VTst  = Kst + 4194304;
        unsigned short* mixed = VTst + 4194304;
        unsigned short* xbf   = (unsigned short*)d_out;     // d_out[0:8MB)
        unsigned short* Qst   = xbf + 4194304;              // d_out[8:16MB)

        convert_all<<<4096, 256, 0, stream>>>(
            (const float*)x, (const float*)WQ, (const float*)WK,
            (const float*)WV, (const float*)Wc, xbf, wbf);

        gemm128<<<dim3(8, 32, 3), 256, 0, stream>>>(
            xbf, wbf, (const float*)bQ, (const float*)bK, (const float*)bV,
            Qst, Kst, VTst, 0);

        attn32p<<<dim3(512, 1), 256, 0, stream>>>(Qst, Kst, VTst, mixed);

        gemm128<<<dim3(8, 32, 1), 256, 0, stream>>>(
            mixed, wbf + 3145728, nullptr, nullptr, nullptr,
            d_out, nullptr, nullptr, 3);
    } else {
        unsigned short* wsK = (unsigned short*)d_ws;
        unsigned short* wsV = wsK + 2097152;
        unsigned short* wsM = wsV + 2097152;
        int* flag = (int*)((char*)d_ws + 12 * 1024 * 1024);

        dtype_probe<<<1, 64, 0, stream>>>((const unsigned short*)x, flag);

        dim3 gg(16, 32), gb(256);
        for (int b = 0; b < 2; ++b) {
            long xo = (long)b * 2048 * 1024;
            gemm_bt<<<gg, gb, 0, stream>>>(x, WQ, bQ, d_out, nullptr, flag, xo, 0, 0, 1);
            gemm_bt<<<gg, gb, 0, stream>>>(x, WK, bK, d_out, wsK, flag, xo, 0, 1, 1);
            gemm_bt<<<gg, gb, 0, stream>>>(x, WV, bV, d_out, wsV, flag, xo, 0, 2, 1);
            attn_kernel<<<dim3(32, 16), 256, 0, stream>>>(d_out, wsK, wsV, wsM, flag);
            gemm_bt<<<gg, gb, 0, stream>>>(wsM, Wc, nullptr, d_out, nullptr, flag,
                                           0, (long)b * 2048 * 1024, 3, 0);
        }
    }
}

// Round 5
// 183.856 us; speedup vs baseline: 1.1067x; 1.1067x over previous
//
#include <hip/hip_runtime.h>

// B=2, L=2048, D=1024, H=16, HD=64. fp32 I/O (confirmed R1-R3), bf16 internals.
// Fast path (ws >= 32MB):
//   convert: x->xbf (d_out lo 8MB), {WQ,WK,WV,Wc}->wbf (ws[0:8MB))
//   fused QKV gemm128 (z=3, global_load_lds staging): Q->d_out hi 8MB [bh][l][hd],
//       K->ws[8:16) [bh][l][hd], VT->ws[16:24) [bh][hd][l]
//   attn32d: swapped-QK 32x32 MFMA flash attention (R2-proven math, verbatim
//       step/softmax/epilogue) with KVBLK=128: each staged iteration covers TWO
//       64-k sub-tiles -> iteration count halves (R2/R4 showed duration tracks
//       staging-iteration count at ~const cost/iter, 5.3us/kiter). Band A does
//       A+1 iterations; pairs {A,15-A} co-reside (stride-256 XCD model).
//       In-register softmax (exp2 domain, no-max), P->A-frag via
//       v_cvt_pk_bf16_f32 + v_permlane32_swap_b32. 512 blocks, 2/CU.
//       -> mixed ws[24:32) [4096][1024] bf16
//   gemm128 (z=1): y = mixed @ Wc^T -> d_out fp32
// Fallback (ws < 32MB): round-3 proven path (probe + per-batch, 12MB).

typedef __bf16 bf16x8 __attribute__((ext_vector_type(8)));
typedef float f32x4 __attribute__((ext_vector_type(4)));
typedef float f32x16 __attribute__((ext_vector_type(16)));
typedef unsigned short us4 __attribute__((ext_vector_type(4)));

#if defined(__has_builtin)
#if __has_builtin(__builtin_amdgcn_global_load_lds)
#define HAS_GLL 1
#endif
#if __has_builtin(__builtin_amdgcn_exp2f)
#define EXP2F(x) __builtin_amdgcn_exp2f(x)
#endif
#endif
#ifndef HAS_GLL
#define HAS_GLL 0
#endif
#ifndef EXP2F
#define EXP2F(x) exp2f(x)
#endif

__device__ __forceinline__ float bf2f(unsigned short u) {
    union { unsigned int i; float f; } v; v.i = ((unsigned int)u) << 16; return v.f;
}
__device__ __forceinline__ unsigned short f2bf(float f) {
    union { float f; unsigned int i; } v; v.f = f;
    unsigned int r = v.i + 0x7FFFu + ((v.i >> 16) & 1u);
    return (unsigned short)(r >> 16);
}
__device__ __forceinline__ f32x4 mfma16(bf16x8 a, bf16x8 b, f32x4 c) {
    return __builtin_amdgcn_mfma_f32_16x16x32_bf16(a, b, c, 0, 0, 0);
}
__device__ __forceinline__ f32x16 mfma32(bf16x8 a, bf16x8 b, f32x16 c) {
    return __builtin_amdgcn_mfma_f32_32x32x16_bf16(a, b, c, 0, 0, 0);
}
__device__ __forceinline__ float clamp4(float v) {
    return fminf(fmaxf(v, -1e4f), 1e4f);
}
union U8 { unsigned short s[8]; bf16x8 v; };

// two f32 -> packed bf16 pair (RNE); no builtin on gfx950 (m240)
__device__ __forceinline__ unsigned int cvt_pk_bf16(float lo, float hi) {
    unsigned int r;
    asm("v_cvt_pk_bf16_f32 %0, %1, %2" : "=v"(r) : "v"(lo), "v"(hi));
    return r;
}
// exchange a.hi32lanes <-> b.lo32lanes (gfx950 cross-half lane swap)
__device__ __forceinline__ void pl32swap(unsigned int& a, unsigned int& b) {
    asm volatile("v_permlane32_swap_b32 %0, %1" : "+v"(a), "+v"(b));
}

#if HAS_GLL
// async global->LDS, 16B/lane. lds ptr must be wave-uniform; HW scatters lane i
// to lds + i*16 (m104: no per-lane LDS scatter, keep dest contiguous).
__device__ __forceinline__ void gl_lds16(const unsigned short* g, unsigned short* l) {
    __builtin_amdgcn_global_load_lds(
        (const __attribute__((address_space(1))) void*)g,
        (__attribute__((address_space(3))) void*)l, 16, 0, 0);
}
#endif

// ------------------------- fast path kernels -------------------------

// 8M elems: [0,4M) x -> xbf; [4M,8M) weights sel=(j>>20) -> wbf+sel*1M.
__global__ __launch_bounds__(256) void convert_all(
    const float* __restrict__ x, const float* __restrict__ WQ,
    const float* __restrict__ WK, const float* __restrict__ WV,
    const float* __restrict__ Wc,
    unsigned short* __restrict__ xbf, unsigned short* __restrict__ wbf)
{
    size_t e = ((size_t)blockIdx.x * 256 + threadIdx.x) * 8;
    const float* src; unsigned short* dst; size_t off;
    if (e < 4194304) { src = x; dst = xbf; off = e; }
    else {
        size_t j = e - 4194304; int sel = (int)(j >> 20); off = j & 1048575;
        src = (sel == 0) ? WQ : (sel == 1) ? WK : (sel == 2) ? WV : Wc;
        dst = wbf + (size_t)sel * 1048576;
    }
    f32x4 a = *(const f32x4*)(src + off);
    f32x4 b = *(const f32x4*)(src + off + 4);
    U8 u;
    u.s[0] = f2bf(a[0]); u.s[1] = f2bf(a[1]); u.s[2] = f2bf(a[2]); u.s[3] = f2bf(a[3]);
    u.s[4] = f2bf(b[0]); u.s[5] = f2bf(b[1]); u.s[6] = f2bf(b[2]); u.s[7] = f2bf(b[3]);
    *(bf16x8*)(dst + off) = u.v;
}

// 128x128 tile, BK=32, 4 waves 2x2, each wave 64x64 (4x4 16x16x32 frags).
// Staging via global_load_lds width=16 (m97 ladder step).
// mode 0: Q -> [bh][l][hd]  mode 1: K -> same  mode 2: VT -> [bh][hd][l]
// mode 3: y -> fp32 [m][n]
__global__ __launch_bounds__(256) void gemm128(
    const unsigned short* __restrict__ A, const unsigned short* __restrict__ Wbase,
    const float* __restrict__ b0, const float* __restrict__ b1, const float* __restrict__ b2,
    void* __restrict__ d0, void* __restrict__ d1, void* __restrict__ d2, int modeBase)
{
    const int z = blockIdx.z;
    const unsigned short* W = Wbase + (size_t)z * 1048576;
    const float* bias = (z == 0) ? b0 : (z == 1) ? b1 : b2;
    void* dst = (z == 0) ? d0 : (z == 1) ? d1 : d2;
    const int mode = modeBase + z;

    __shared__ __align__(16) unsigned short At[128][32];
    __shared__ __align__(16) unsigned short Bt[128][32];

    const int mb = blockIdx.y * 128, nb = blockIdx.x * 128;
    const int tid = threadIdx.x, w = tid >> 6, lane = tid & 63;
    const int wr = w >> 1, wc = w & 1;
    const int col = lane & 15, quad = lane >> 4;

    f32x4 acc[4][4];
    for (int i = 0; i < 4; ++i) for (int j = 0; j < 4; ++j) acc[i][j] = (f32x4){0.f, 0.f, 0.f, 0.f};

#if HAS_GLL
    // wave w stages rows [w*32, w*32+32): lane l -> row w*32 + l/4, chunk (l&3)*8
    const unsigned short* ga = A + (size_t)(mb + w * 32 + (lane >> 2)) * 1024 + (lane & 3) * 8;
    const unsigned short* gw = W + (size_t)(nb + w * 32 + (lane >> 2)) * 1024 + (lane & 3) * 8;
    unsigned short* lA0 = &At[w * 32][0];        // wave-uniform bases
    unsigned short* lA1 = &At[w * 32 + 16][0];
    unsigned short* lB0 = &Bt[w * 32][0];
    unsigned short* lB1 = &Bt[w * 32 + 16][0];
#else
    const int srow = w * 32 + (lane >> 1);
    const int scol = (lane & 1) * 16;
    const unsigned short* Ab = A + (size_t)(mb + srow) * 1024 + scol;
    const unsigned short* Wb = W + (size_t)(nb + srow) * 1024 + scol;
#endif

    for (int kb = 0; kb < 1024; kb += 32) {
#if HAS_GLL
        gl_lds16(ga + kb, lA0);
        gl_lds16(ga + kb + 16 * 1024, lA1);
        gl_lds16(gw + kb, lB0);
        gl_lds16(gw + kb + 16 * 1024, lB1);
#else
        *(bf16x8*)&At[srow][scol]     = *(const bf16x8*)(Ab + kb);
        *(bf16x8*)&At[srow][scol + 8] = *(const bf16x8*)(Ab + kb + 8);
        *(bf16x8*)&Bt[srow][scol]     = *(const bf16x8*)(Wb + kb);
        *(bf16x8*)&Bt[srow][scol + 8] = *(const bf16x8*)(Wb + kb + 8);
#endif
        __syncthreads();
        bf16x8 a[4], b[4];
        for (int i = 0; i < 4; ++i) a[i] = *(const bf16x8*)&At[wr * 64 + i * 16 + col][quad * 8];
        for (int j = 0; j < 4; ++j) b[j] = *(const bf16x8*)&Bt[wc * 64 + j * 16 + col][quad * 8];
        for (int i = 0; i < 4; ++i)
            for (int j = 0; j < 4; ++j)
                acc[i][j] = mfma16(a[i], b[j], acc[i][j]);
        __syncthreads();
    }

    for (int i = 0; i < 4; ++i) {
        const int mbase = mb + wr * 64 + i * 16 + quad * 4;
        const int bb = mbase >> 11, l = mbase & 2047;
        for (int j = 0; j < 4; ++j) {
            const int n = nb + wc * 64 + j * 16 + col;
            const float bv = bias ? bias[n] : 0.f;
            if (mode == 3) {
                float* o = (float*)dst;
                for (int r = 0; r < 4; ++r)
                    o[(size_t)(mbase + r) * 1024 + n] = clamp4(acc[i][j][r] + bv);
            } else if (mode == 2) {
                const int h = n >> 6, hd = n & 63;
                us4 pk;
                for (int r = 0; r < 4; ++r) pk[r] = f2bf(clamp4(acc[i][j][r] + bv));
                *(us4*)((unsigned short*)dst + (size_t)(bb * 16 + h) * 131072
                        + (size_t)hd * 2048 + l) = pk;
            } else {
                const int h = n >> 6, hd = n & 63;
                unsigned short* o = (unsigned short*)dst + (size_t)(bb * 16 + h) * 131072
                                    + (size_t)l * 64 + hd;
                for (int r = 0; r < 4; ++r)
                    o[(size_t)r * 64] = f2bf(clamp4(acc[i][j][r] + bv));
            }
        }
    }
}

// ---- attn32d: swapped-QK 32x32 in-register-softmax flash attention ----
// S^T acc layout (m74/m101): col q = lane&31; k = (reg&3) + 8*(reg>>2) + 4*hi.
// A-frag build (m214 recipe): pairs (r,r+1) cvt_pk'd, (r0..) swapped with (r4..)
// via v_permlane32_swap: first -> [lo,lo] word, second -> [hi,hi] word.
// (soft_pack / step math verbatim the R2-passing code.)

template<bool DIAG>
__device__ __forceinline__ void soft_pack(
    const f32x16& sacc, bf16x8* pa, float& lpart, int kg0, int qg)
{
    float p[16];
#pragma unroll
    for (int r = 0; r < 16; ++r) {
        float v = sacc[r] * 0.18033688f;   // 0.125 * log2(e): exp2 domain
        if (DIAG) {
            int kg = kg0 + (r & 3) + 8 * (r >> 2);
            if (kg > qg) v = -1e30f;
        }
        v = fminf(v, 86.5f);               // overflow guard (== e-domain 60)
        p[r] = EXP2F(v);
    }
    float t0 = (p[0] + p[1]) + (p[2] + p[3]);
    float t1 = (p[4] + p[5]) + (p[6] + p[7]);
    float t2 = (p[8] + p[9]) + (p[10] + p[11]);
    float t3 = (p[12] + p[13]) + (p[14] + p[15]);
    lpart += (t0 + t1) + (t2 + t3);
#pragma unroll
    for (int c = 0; c < 2; ++c) {
        unsigned int a0 = cvt_pk_bf16(p[8*c + 0], p[8*c + 1]);
        unsigned int b0 = cvt_pk_bf16(p[8*c + 4], p[8*c + 5]);
        unsigned int a1 = cvt_pk_bf16(p[8*c + 2], p[8*c + 3]);
        unsigned int b1 = cvt_pk_bf16(p[8*c + 6], p[8*c + 7]);
        pl32swap(a0, b0);                  // a0 -> w0 (lo:k01 / hi:k89), b0 -> w2
        pl32swap(a1, b1);                  // a1 -> w1,                  b1 -> w3
        union PW { unsigned int w[4]; bf16x8 v; } pw;
        pw.w[0] = a0; pw.w[1] = a1; pw.w[2] = b0; pw.w[3] = b1;
        pa[c] = pw.v;
    }
}

// One 64-k sub-tile step. Kt: 64-row sub-tile base (stride 72). Vt: pointer to
// &V_lds[0][col0], row stride 136 (64 hd rows x 128 k cols tile).
template<bool DIAG>
__device__ __forceinline__ void attn32_step2(
    const unsigned short (*__restrict__ Kt)[72], const unsigned short* __restrict__ Vt,
    const bf16x8* __restrict__ qf, f32x16* __restrict__ oacc, float& lpart,
    int kb, int qg, int hi, int c31)
{
    f32x16 s0, s1;
#pragma unroll
    for (int r = 0; r < 16; ++r) { s0[r] = 0.f; s1[r] = 0.f; }
#pragma unroll
    for (int dc = 0; dc < 4; ++dc) {
        bf16x8 kf0 = *(const bf16x8*)&Kt[c31][dc * 16 + hi * 8];
        bf16x8 kf1 = *(const bf16x8*)&Kt[32 + c31][dc * 16 + hi * 8];
        s0 = mfma32(kf0, qf[dc], s0);
        s1 = mfma32(kf1, qf[dc], s1);
    }
    bf16x8 pa[4];
    soft_pack<DIAG>(s0, pa,     lpart, kb + 4 * hi,      qg);
    soft_pack<DIAG>(s1, pa + 2, lpart, kb + 32 + 4 * hi, qg);
#pragma unroll
    for (int b2 = 0; b2 < 2; ++b2)
#pragma unroll
        for (int kc = 0; kc < 4; ++kc) {
            bf16x8 vf = *(const bf16x8*)&Vt[(size_t)(b2 * 32 + c31) * 136 + kc * 16 + hi * 8];
            oacc[b2] = mfma32(pa[kc], vf, oacc[b2]);
        }
}

__device__ __forceinline__ void attn_write32(
    unsigned short* __restrict__ mixed, int gb, int h, int q0, int c31, int hi,
    const f32x16* __restrict__ oacc, const float* __restrict__ lrow)
{
    f32x4 iv[4];
#pragma unroll
    for (int m = 0; m < 4; ++m) {
        f32x4 lv = *(const f32x4*)&lrow[4 * hi + 8 * m];
#pragma unroll
        for (int r = 0; r < 4; ++r) iv[m][r] = 1.f / lv[r];
    }
#pragma unroll
    for (int b2 = 0; b2 < 2; ++b2)
#pragma unroll
        for (int r = 0; r < 16; ++r) {
            const int qrow = q0 + 4 * hi + (r & 3) + 8 * (r >> 2);
            const float val = clamp4(oacc[b2][r] * iv[r >> 2][r & 3]);
            mixed[(size_t)(gb * 2048 + qrow) * 1024 + h * 64 + b2 * 32 + c31] = f2bf(val);
        }
}

// Wave = 32 q-rows, block = 4 waves = 128-row band A (0..15). KVBLK=128: each
// staged iteration jj covers 64-k sub-tiles t0=2jj, t1=2jj+1; band A runs A+1
// iterations (half of R2's 2A+2). Diagonal: ss = 2A + (w>>1); on the last
// iteration sub-tile t==ss gets the mask, t>ss skipped. Pairs {A,15-A}
// co-reside via stride-256 XCD model. Grid 512 = {pair sel kk, bh, j}.
// Q,K: [bh][l][hd]; V: [bh][hd][l]; mixed: [4096][1024] bf16.
__global__ __launch_bounds__(256, 2) void attn32d(
    const unsigned short* __restrict__ Q, const unsigned short* __restrict__ K,
    const unsigned short* __restrict__ V, unsigned short* __restrict__ mixed)
{
    const int lb = blockIdx.x;
    const int i = lb & 255, kk = lb >> 8;
    const int bh = i & 31, j = i >> 5;        // j in [0,8)
    const int A = kk ? (15 - j) : j;          // 128-row band index 0..15
    const int niter = A + 1;                  // 128-wide k iterations

    const int tid = threadIdx.x, w = tid >> 6, lane = tid & 63;
    const int c31 = lane & 31, hi = lane >> 5;

    __shared__ __align__(16) unsigned short Kt[128][72];
    __shared__ __align__(16) unsigned short Vt[64][136];
    __shared__ __align__(16) float lslab[4][32];

    const unsigned short* Qb = Q + (size_t)bh * 131072;
    const unsigned short* Kb = K + (size_t)bh * 131072;
    const unsigned short* Vb = V + (size_t)bh * 131072;

    const int q0 = A * 128 + w * 32;
    const int qg = q0 + c31;                  // this lane's global q-row
    const int ss = 2 * A + (w >> 1);          // diagonal 64-sub-tile index

    bf16x8 qf[4];
    {
        const unsigned short* Qr = Qb + (size_t)qg * 64 + hi * 8;
#pragma unroll
        for (int dc = 0; dc < 4; ++dc) qf[dc] = *(const bf16x8*)(Qr + dc * 16);
    }

    f32x16 oacc[2];
#pragma unroll
    for (int b2 = 0; b2 < 2; ++b2)
#pragma unroll
        for (int r = 0; r < 16; ++r) oacc[b2][r] = 0.f;
    float lpart = 0.f;

    const int sr = tid >> 3, sc = (tid & 7) * 8;   // 32-row x 64-col write set

    // prefetch iteration 0: K rows 0..127 (4 sets), V cols 0..127 (2x2 sets)
    const unsigned short* kp = Kb + (size_t)sr * 64 + sc;
    const unsigned short* vp = Vb + (size_t)sr * 2048 + sc;
    bf16x8 pk0 = *(const bf16x8*)kp;
    bf16x8 pk1 = *(const bf16x8*)(kp + 32 * 64);
    bf16x8 pk2 = *(const bf16x8*)(kp + 64 * 64);
    bf16x8 pk3 = *(const bf16x8*)(kp + 96 * 64);
    bf16x8 pv0 = *(const bf16x8*)vp;
    bf16x8 pv1 = *(const bf16x8*)(vp + 32 * 2048);
    bf16x8 pv2 = *(const bf16x8*)(vp + 64);
    bf16x8 pv3 = *(const bf16x8*)(vp + 32 * 2048 + 64);

    for (int jj = 0; jj < niter; ++jj) {
        __syncthreads();                     // prior iter's LDS reads complete
        *(bf16x8*)&Kt[sr][sc]       = pk0;
        *(bf16x8*)&Kt[sr + 32][sc]  = pk1;
        *(bf16x8*)&Kt[sr + 64][sc]  = pk2;
        *(bf16x8*)&Kt[sr + 96][sc]  = pk3;
        *(bf16x8*)&Vt[sr][sc]       = pv0;
        *(bf16x8*)&Vt[sr + 32][sc]  = pv1;
        *(bf16x8*)&Vt[sr][64 + sc]  = pv2;
        *(bf16x8*)&Vt[sr + 32][64 + sc] = pv3;
        __syncthreads();
        if (jj + 1 < niter) {                // issue next iter's loads now:
            const int kb2 = (jj + 1) * 128;  // latency overlaps this iter's compute
            const unsigned short* kp2 = Kb + (size_t)(kb2 + sr) * 64 + sc;
            const unsigned short* vp2 = Vb + (size_t)sr * 2048 + kb2 + sc;
            pk0 = *(const bf16x8*)kp2;
            pk1 = *(const bf16x8*)(kp2 + 32 * 64);
            pk2 = *(const bf16x8*)(kp2 + 64 * 64);
            pk3 = *(const bf16x8*)(kp2 + 96 * 64);
            pv0 = *(const bf16x8*)vp2;
            pv1 = *(const bf16x8*)(vp2 + 32 * 2048);
            pv2 = *(const bf16x8*)(vp2 + 64);
            pv3 = *(const bf16x8*)(vp2 + 32 * 2048 + 64);
        }
        const int t0 = 2 * jj, t1 = t0 + 1;
        // sub-tile 0: K rows [0,64), V cols [0,64)
        if (t0 < ss)
            attn32_step2<false>(&Kt[0], &Vt[0][0],  qf, oacc, lpart, t0 * 64, qg, hi, c31);
        else if (t0 == ss)
            attn32_step2<true >(&Kt[0], &Vt[0][0],  qf, oacc, lpart, t0 * 64, qg, hi, c31);
        // sub-tile 1: K rows [64,128), V cols [64,128)
        if (t1 < ss)
            attn32_step2<false>(&Kt[64], &Vt[0][64], qf, oacc, lpart, t1 * 64, qg, hi, c31);
        else if (t1 == ss)
            attn32_step2<true >(&Kt[64], &Vt[0][64], qf, oacc, lpart, t1 * 64, qg, hi, c31);
        // t > ss: fully masked, skip (waves 0,1 on the last iteration)
    }

    // row-sum: combine lane-half partials, stash per-q, regather in reg-q order
    float ltot = lpart + __shfl_xor(lpart, 32, 64);
    if (lane < 32) lslab[w][lane] = ltot;    // q = lane (intra-wave ordered)

    const int gb = bh >> 4, h = bh & 15;
    attn_write32(mixed, gb, h, q0, c31, hi, oacc, &lslab[w][0]);
}

// ------------------------- fallback (round-3 proven) -------------------------

__device__ __forceinline__ bf16x8 load8(const void* base, size_t eoff, int asF32) {
    if (asF32) {
        const float* p = (const float*)base + eoff;
        f32x4 a = *(const f32x4*)p;
        f32x4 b = *(const f32x4*)(p + 4);
        U8 u;
        u.s[0]=f2bf(a[0]); u.s[1]=f2bf(a[1]); u.s[2]=f2bf(a[2]); u.s[3]=f2bf(a[3]);
        u.s[4]=f2bf(b[0]); u.s[5]=f2bf(b[1]); u.s[6]=f2bf(b[2]); u.s[7]=f2bf(b[3]);
        return u.v;
    }
    return *(const bf16x8*)((const unsigned short*)base + eoff);
}

__global__ void dtype_probe(const unsigned short* __restrict__ x, int* __restrict__ flag) {
    if (threadIdx.x == 0) {
        int c = 0;
        for (int i = 0; i < 128; ++i) {
            int e = (x[2 * i] >> 7) & 0xFF;
            if (e >= 100 && e <= 135) ++c;
        }
        *flag = (c < 64) ? 1 : 0;
    }
}

__global__ __launch_bounds__(256) void gemm_bt(
    const void* __restrict__ Ap, const void* __restrict__ Wp,
    const void* __restrict__ biasp, void* __restrict__ dout,
    unsigned short* __restrict__ wsdst, const int* __restrict__ flag,
    long aOff, long outOff, int mode, int aFlagged)
{
    const int f32 = *flag;
    __shared__ __align__(16) unsigned short At[64][32];
    __shared__ __align__(16) unsigned short Bt[64][32];
    const int mb = blockIdx.y * 64, nb = blockIdx.x * 64;
    const int tid = threadIdx.x;
    const int w = tid >> 6, lane = tid & 63;
    const int wr = w >> 1, wc = w & 1;
    const int col = lane & 15, quad = lane >> 4;
    const int srow = tid >> 2, schunk = (tid & 3) * 8;
    const int aF = aFlagged && f32;

    f32x4 acc[2][2];
    for (int i = 0; i < 2; ++i) for (int j = 0; j < 2; ++j) acc[i][j] = (f32x4){0.f,0.f,0.f,0.f};

    const size_t aBase = (size_t)aOff + (size_t)(mb + srow) * 1024 + schunk;
    const size_t wBase = (size_t)(nb + srow) * 1024 + schunk;

    for (int kb = 0; kb < 1024; kb += 32) {
        *(bf16x8*)(&At[srow][schunk]) = load8(Ap, aBase + kb, aF);
        *(bf16x8*)(&Bt[srow][schunk]) = load8(Wp, wBase + kb, f32);
        __syncthreads();
        bf16x8 a0 = *(const bf16x8*)(&At[wr * 32 + col][quad * 8]);
        bf16x8 a1 = *(const bf16x8*)(&At[wr * 32 + 16 + col][quad * 8]);
        bf16x8 b0 = *(const bf16x8*)(&Bt[wc * 32 + col][quad * 8]);
        bf16x8 b1 = *(const bf16x8*)(&Bt[wc * 32 + 16 + col][quad * 8]);
        acc[0][0] = mfma16(a0, b0, acc[0][0]);
        acc[0][1] = mfma16(a0, b1, acc[0][1]);
        acc[1][0] = mfma16(a1, b0, acc[1][0]);
        acc[1][1] = mfma16(a1, b1, acc[1][1]);
        __syncthreads();
    }

    for (int mi = 0; mi < 2; ++mi) {
        for (int ni = 0; ni < 2; ++ni) {
            int n = nb + wc * 32 + ni * 16 + col;
            float bv = 0.f;
            if (biasp) bv = f32 ? ((const float*)biasp)[n] : bf2f(((const unsigned short*)biasp)[n]);
            for (int r = 0; r < 4; ++r) {
                int m = mb + wr * 32 + mi * 16 + quad * 4 + r;
                float v = clamp4(acc[mi][ni][r] + bv);
                if (mode == 3) {
                    size_t idx = (size_t)outOff + (size_t)m * 1024 + n;
                    if (f32) ((float*)dout)[idx] = v;
                    else     ((unsigned short*)dout)[idx] = f2bf(v);
                } else {
                    int h = n >> 6, hd = n & 63;
                    size_t idx = (mode == 2)
                        ? (size_t)h * 131072 + (size_t)hd * 2048 + m
                        : (size_t)h * 131072 + (size_t)m * 64 + hd;
                    unsigned short* dstp = (mode == 0)
                        ? (unsigned short*)dout + (f32 ? 4194304 : 2097152)
                        : wsdst;
                    dstp[idx] = f2bf(v);
                }
            }
        }
    }
}

__global__ __launch_bounds__(256) void attn_kernel(
    const void* __restrict__ dout, const unsigned short* __restrict__ Kw,
    const unsigned short* __restrict__ Vw, unsigned short* __restrict__ mixed,
    const int* __restrict__ flag)
{
    const int f32 = *flag;
    const int qtile = blockIdx.x;
    const int h = blockIdx.y;
    const int w = threadIdx.x >> 6, lane = threadIdx.x & 63;
    const int col = lane & 15, quad = lane >> 4;

    __shared__ __align__(16) unsigned short Plds[4][16][64];

    const unsigned short* Qs = (const unsigned short*)dout + (f32 ? 4194304 : 2097152);
    const unsigned short* Qb = Qs + (size_t)h * 131072;
    const unsigned short* Kb = Kw + (size_t)h * 131072;
    const unsigned short* Vb = Vw + (size_t)h * 131072;

    const int q0 = qtile * 64 + w * 16;
    bf16x8 aq0 = *(const bf16x8*)(Qb + (size_t)(q0 + col) * 64 + quad * 8);
    bf16x8 aq1 = *(const bf16x8*)(Qb + (size_t)(q0 + col) * 64 + 32 + quad * 8);

    float m_run[4] = {-1e30f, -1e30f, -1e30f, -1e30f};
    float l_run[4] = {0.f, 0.f, 0.f, 0.f};
    f32x4 oacc[4];
    for (int i = 0; i < 4; ++i) oacc[i] = (f32x4){0.f, 0.f, 0.f, 0.f};

    for (int kt = 0; kt <= qtile; ++kt) {
        const int kb = kt * 64;
        f32x4 s[4];
        for (int t = 0; t < 4; ++t) {
            s[t] = (f32x4){0.f, 0.f, 0.f, 0.f};
            bf16x8 bk0 = *(const bf16x8*)(Kb + (size_t)(kb + t * 16 + col) * 64 + quad * 8);
            bf16x8 bk1 = *(const bf16x8*)(Kb + (size_t)(kb + t * 16 + col) * 64 + 32 + quad * 8);
            s[t] = mfma16(aq0, bk0, s[t]);
            s[t] = mfma16(aq1, bk1, s[t]);
        }
        for (int t = 0; t < 4; ++t)
            for (int r = 0; r < 4; ++r) {
                float v = clamp4(s[t][r] * 0.125f);
                if (kt == qtile && (t * 16 + col > w * 16 + quad * 4 + r)) v = -1e30f;
                s[t][r] = v;
            }
        float mt[4];
        for (int r = 0; r < 4; ++r)
            mt[r] = fmaxf(fmaxf(s[0][r], s[1][r]), fmaxf(s[2][r], s[3][r]));
        for (int off = 1; off < 16; off <<= 1)
            for (int r = 0; r < 4; ++r)
                mt[r] = fmaxf(mt[r], __shfl_xor(mt[r], off, 64));
        float alpha[4], rs[4], p[4][4];
        for (int r = 0; r < 4; ++r) {
            float mn = fmaxf(m_run[r], mt[r]);
            alpha[r] = __expf(m_run[r] - mn);
            m_run[r] = mn;
        }
        for (int t = 0; t < 4; ++t)
            for (int r = 0; r < 4; ++r)
                p[t][r] = __expf(s[t][r] - m_run[r]);
        for (int r = 0; r < 4; ++r)
            rs[r] = (p[0][r] + p[1][r]) + (p[2][r] + p[3][r]);
        for (int off = 1; off < 16; off <<= 1)
            for (int r = 0; r < 4; ++r)
                rs[r] += __shfl_xor(rs[r], off, 64);
        for (int r = 0; r < 4; ++r)
            l_run[r] = l_run[r] * alpha[r] + rs[r];
        for (int nt = 0; nt < 4; ++nt)
            for (int r = 0; r < 4; ++r)
                oacc[nt][r] *= alpha[r];
        for (int t = 0; t < 4; ++t)
            for (int r = 0; r < 4; ++r)
                Plds[w][quad * 4 + r][t * 16 + col] = f2bf(p[t][r]);
        __syncthreads();
        bf16x8 ap0 = *(const bf16x8*)(&Plds[w][col][quad * 8]);
        bf16x8 ap1 = *(const bf16x8*)(&Plds[w][col][32 + quad * 8]);
        for (int nt = 0; nt < 4; ++nt) {
            bf16x8 bv0 = *(const bf16x8*)(Vb + (size_t)(nt * 16 + col) * 2048 + kb + quad * 8);
            bf16x8 bv1 = *(const bf16x8*)(Vb + (size_t)(nt * 16 + col) * 2048 + kb + 32 + quad * 8);
            oacc[nt] = mfma16(ap0, bv0, oacc[nt]);
            oacc[nt] = mfma16(ap1, bv1, oacc[nt]);
        }
        __syncthreads();
    }

    float inv[4];
    for (int r = 0; r < 4; ++r) inv[r] = 1.f / l_run[r];
    for (int nt = 0; nt < 4; ++nt)
        for (int r = 0; r < 4; ++r) {
            int qrow = q0 + quad * 4 + r;
            mixed[(size_t)qrow * 1024 + h * 64 + nt * 16 + col] = f2bf(clamp4(oacc[nt][r] * inv[r]));
        }
}

// ------------------------- launcher -------------------------

extern "C" void kernel_launch(void* const* d_in, const int* in_sizes, int n_in,
                              void* d_out, int out_size, void* d_ws, size_t ws_size,
                              hipStream_t stream) {
    (void)in_sizes; (void)n_in; (void)out_size;
    const void* x  = d_in[0];
    const void* WQ = d_in[1]; const void* bQ = d_in[2];
    const void* WK = d_in[3]; const void* bK = d_in[4];
    const void* WV = d_in[5]; const void* bV = d_in[6];
    const void* Wc = d_in[7];

    if (ws_size >= (size_t)32 * 1024 * 1024) {
        unsigned short* wbf   = (unsigned short*)d_ws;      // 4M elems (8MB)
        unsigned short* Kst   = wbf + 4194304;
        unsigned short* VTst  = Kst + 4194304;
        unsigned short* mixed = VTst + 4194304;
        unsigned short* xbf   = (unsigned short*)d_out;     // d_out[0:8MB)
        unsigned short* Qst   = xbf + 4194304;              // d_out[8:16MB)

        convert_all<<<4096, 256, 0, stream>>>(
            (const float*)x, (const float*)WQ, (const float*)WK,
            (const float*)WV, (const float*)Wc, xbf, wbf);

        gemm128<<<dim3(8, 32, 3), 256, 0, stream>>>(
            xbf, wbf, (const float*)bQ, (const float*)bK, (const float*)bV,
            Qst, Kst, VTst, 0);

        attn32d<<<dim3(512, 1), 256, 0, stream>>>(Qst, Kst, VTst, mixed);

        gemm128<<<dim3(8, 32, 1), 256, 0, stream>>>(
            mixed, wbf + 3145728, nullptr, nullptr, nullptr,
            d_out, nullptr, nullptr, 3);
    } else {
        unsigned short* wsK = (unsigned short*)d_ws;
        unsigned short* wsV = wsK + 2097152;
        unsigned short* wsM = wsV + 2097152;
        int* flag = (int*)((char*)d_ws + 12 * 1024 * 1024);

        dtype_probe<<<1, 64, 0, stream>>>((const unsigned short*)x, flag);

        dim3 gg(16, 32), gb(256);
        for (int b = 0; b < 2; ++b) {
            long xo = (long)b * 2048 * 1024;
            gemm_bt<<<gg, gb, 0, stream>>>(x, WQ, bQ, d_out, nullptr, flag, xo, 0, 0, 1);
            gemm_bt<<<gg, gb, 0, stream>>>(x, WK, bK, d_out, wsK, flag, xo, 0, 1, 1);
            gemm_bt<<<gg, gb, 0, stream>>>(x, WV, bV, d_out, wsV, flag, xo, 0, 2, 1);
            attn_kernel<<<dim3(32, 16), 256, 0, stream>>>(d_out, wsK, wsV, wsM, flag);
            gemm_bt<<<gg, gb, 0, stream>>>(wsM, Wc, nullptr, d_out, nullptr, flag,
                                           0, (long)b * 2048 * 1024, 3, 0);
        }
    }
}

// Round 6
// 179.293 us; speedup vs baseline: 1.1348x; 1.0254x over previous
//
#include <hip/hip_runtime.h>

// B=2, L=2048, D=1024, H=16, HD=64. fp32 I/O (confirmed R1-R3), bf16 internals.
// Fast path (ws >= 32MB):
//   convert: x->xbf (d_out lo 8MB), {WQ,WK,WV,Wc}->wbf (ws[0:8MB))
//   fused QKV gemm128 (z=3): BK=64 (16 staged iterations, R4/R5 fewer-fatter
//       lesson) + T2 chunk-XOR swizzle (source-preswizzled global_load_lds +
//       swizzled ds_read, rule-21 both-sides) -> 2-way (free) frag reads vs
//       8-way at the old [128][32]. Q->d_out hi 8MB [bh][l][hd],
//       K->ws[8:16) [bh][l][hd], VT->ws[16:24) [bh][hd][l]
//   attn32d: swapped-QK 32x32 MFMA flash attention, KVBLK=128 (R5-proven).
//       In-register softmax (exp2 domain, no-max), P->A-frag via
//       v_cvt_pk_bf16_f32 + v_permlane32_swap_b32. 512 blocks, 2/CU,
//       pairs {A,15-A} co-reside. -> mixed ws[24:32) [4096][1024] bf16
//   gemm128 (z=1): y = mixed @ Wc^T -> d_out fp32
// Fallback (ws < 32MB): round-3 proven path (probe + per-batch, 12MB).

typedef __bf16 bf16x8 __attribute__((ext_vector_type(8)));
typedef float f32x4 __attribute__((ext_vector_type(4)));
typedef float f32x16 __attribute__((ext_vector_type(16)));
typedef unsigned short us4 __attribute__((ext_vector_type(4)));

#if defined(__has_builtin)
#if __has_builtin(__builtin_amdgcn_global_load_lds)
#define HAS_GLL 1
#endif
#if __has_builtin(__builtin_amdgcn_exp2f)
#define EXP2F(x) __builtin_amdgcn_exp2f(x)
#endif
#endif
#ifndef HAS_GLL
#define HAS_GLL 0
#endif
#ifndef EXP2F
#define EXP2F(x) exp2f(x)
#endif

__device__ __forceinline__ float bf2f(unsigned short u) {
    union { unsigned int i; float f; } v; v.i = ((unsigned int)u) << 16; return v.f;
}
__device__ __forceinline__ unsigned short f2bf(float f) {
    union { float f; unsigned int i; } v; v.f = f;
    unsigned int r = v.i + 0x7FFFu + ((v.i >> 16) & 1u);
    return (unsigned short)(r >> 16);
}
__device__ __forceinline__ f32x4 mfma16(bf16x8 a, bf16x8 b, f32x4 c) {
    return __builtin_amdgcn_mfma_f32_16x16x32_bf16(a, b, c, 0, 0, 0);
}
__device__ __forceinline__ f32x16 mfma32(bf16x8 a, bf16x8 b, f32x16 c) {
    return __builtin_amdgcn_mfma_f32_32x32x16_bf16(a, b, c, 0, 0, 0);
}
__device__ __forceinline__ float clamp4(float v) {
    return fminf(fmaxf(v, -1e4f), 1e4f);
}
union U8 { unsigned short s[8]; bf16x8 v; };

// two f32 -> packed bf16 pair (RNE); no builtin on gfx950 (m240)
__device__ __forceinline__ unsigned int cvt_pk_bf16(float lo, float hi) {
    unsigned int r;
    asm("v_cvt_pk_bf16_f32 %0, %1, %2" : "=v"(r) : "v"(lo), "v"(hi));
    return r;
}
// exchange a.hi32lanes <-> b.lo32lanes (gfx950 cross-half lane swap)
__device__ __forceinline__ void pl32swap(unsigned int& a, unsigned int& b) {
    asm volatile("v_permlane32_swap_b32 %0, %1" : "+v"(a), "+v"(b));
}

#if HAS_GLL
// async global->LDS, 16B/lane. lds ptr must be wave-uniform; HW scatters lane i
// to lds + i*16 (m104: no per-lane LDS scatter, keep dest contiguous).
__device__ __forceinline__ void gl_lds16(const unsigned short* g, unsigned short* l) {
    __builtin_amdgcn_global_load_lds(
        (const __attribute__((address_space(1))) void*)g,
        (__attribute__((address_space(3))) void*)l, 16, 0, 0);
}
#endif

// ------------------------- fast path kernels -------------------------

// 8M elems: [0,4M) x -> xbf; [4M,8M) weights sel=(j>>20) -> wbf+sel*1M.
__global__ __launch_bounds__(256) void convert_all(
    const float* __restrict__ x, const float* __restrict__ WQ,
    const float* __restrict__ WK, const float* __restrict__ WV,
    const float* __restrict__ Wc,
    unsigned short* __restrict__ xbf, unsigned short* __restrict__ wbf)
{
    size_t e = ((size_t)blockIdx.x * 256 + threadIdx.x) * 8;
    const float* src; unsigned short* dst; size_t off;
    if (e < 4194304) { src = x; dst = xbf; off = e; }
    else {
        size_t j = e - 4194304; int sel = (int)(j >> 20); off = j & 1048575;
        src = (sel == 0) ? WQ : (sel == 1) ? WK : (sel == 2) ? WV : Wc;
        dst = wbf + (size_t)sel * 1048576;
    }
    f32x4 a = *(const f32x4*)(src + off);
    f32x4 b = *(const f32x4*)(src + off + 4);
    U8 u;
    u.s[0] = f2bf(a[0]); u.s[1] = f2bf(a[1]); u.s[2] = f2bf(a[2]); u.s[3] = f2bf(a[3]);
    u.s[4] = f2bf(b[0]); u.s[5] = f2bf(b[1]); u.s[6] = f2bf(b[2]); u.s[7] = f2bf(b[3]);
    *(bf16x8*)(dst + off) = u.v;
}

// 128x128 tile, BK=64, 4 waves 2x2, each wave 64x64 (4x4 16x16x32 frags, 2 k-
// chunks per iter = 32 MFMA). T2 swizzle: LDS [128][64] linear (gl_lds dest),
// 16B-chunk index XOR'd with (row&7) on BOTH the global source address and the
// ds_read — frag reads land 2 lanes/bank (free) instead of 8-way at [128][32].
// mode 0: Q -> [bh][l][hd]  mode 1: K -> same  mode 2: VT -> [bh][hd][l]
// mode 3: y -> fp32 [m][n]
__global__ __launch_bounds__(256) void gemm128(
    const unsigned short* __restrict__ A, const unsigned short* __restrict__ Wbase,
    const float* __restrict__ b0, const float* __restrict__ b1, const float* __restrict__ b2,
    void* __restrict__ d0, void* __restrict__ d1, void* __restrict__ d2, int modeBase)
{
    const int z = blockIdx.z;
    const unsigned short* W = Wbase + (size_t)z * 1048576;
    const float* bias = (z == 0) ? b0 : (z == 1) ? b1 : b2;
    void* dst = (z == 0) ? d0 : (z == 1) ? d1 : d2;
    const int mode = modeBase + z;

    __shared__ __align__(16) unsigned short At[128][64];
    __shared__ __align__(16) unsigned short Bt[128][64];

    const int mb = blockIdx.y * 128, nb = blockIdx.x * 128;
    const int tid = threadIdx.x, w = tid >> 6, lane = tid & 63;
    const int wr = w >> 1, wc = w & 1;
    const int col = lane & 15, quad = lane >> 4;

    f32x4 acc[4][4];
    for (int i = 0; i < 4; ++i) for (int j = 0; j < 4; ++j) acc[i][j] = (f32x4){0.f, 0.f, 0.f, 0.f};

#if HAS_GLL
    // wave w stages rows [w*32, w*32+32) in 4 calls of 8 rows each.
    // lane l -> row sub-offset l>>3, source chunk (l&7) ^ (l>>3)  [inverse swz]
    const int srow8 = lane >> 3;                 // 0..7 (== row&7 for all calls)
    const int scs   = (lane & 7) ^ srow8;        // pre-swizzled source chunk
    const unsigned short* ga = A + (size_t)(mb + w * 32 + srow8) * 1024 + scs * 8;
    const unsigned short* gw = W + (size_t)(nb + w * 32 + srow8) * 1024 + scs * 8;
    unsigned short* lA0 = &At[w * 32][0];        // wave-uniform bases
    unsigned short* lA1 = &At[w * 32 + 8][0];
    unsigned short* lA2 = &At[w * 32 + 16][0];
    unsigned short* lA3 = &At[w * 32 + 24][0];
    unsigned short* lB0 = &Bt[w * 32][0];
    unsigned short* lB1 = &Bt[w * 32 + 8][0];
    unsigned short* lB2 = &Bt[w * 32 + 16][0];
    unsigned short* lB3 = &Bt[w * 32 + 24][0];
#else
    const int srow = tid >> 1;                   // 0..127
    const int sc4  = (tid & 1) * 4;              // chunk base 0 / 4
    const unsigned short* Ab = A + (size_t)(mb + srow) * 1024;
    const unsigned short* Wb = W + (size_t)(nb + srow) * 1024;
#endif

    for (int kb = 0; kb < 1024; kb += 64) {
#if HAS_GLL
        gl_lds16(ga + kb, lA0);
        gl_lds16(ga + kb +  8 * 1024, lA1);
        gl_lds16(ga + kb + 16 * 1024, lA2);
        gl_lds16(ga + kb + 24 * 1024, lA3);
        gl_lds16(gw + kb, lB0);
        gl_lds16(gw + kb +  8 * 1024, lB1);
        gl_lds16(gw + kb + 16 * 1024, lB2);
        gl_lds16(gw + kb + 24 * 1024, lB3);
#else
        for (int cc = 0; cc < 4; ++cc) {
            const int ch = sc4 + cc, chs = ch ^ (srow & 7);
            *(bf16x8*)&At[srow][chs * 8] = *(const bf16x8*)(Ab + kb + ch * 8);
            *(bf16x8*)&Bt[srow][chs * 8] = *(const bf16x8*)(Wb + kb + ch * 8);
        }
#endif
        __syncthreads();
        bf16x8 a[4][2], b[4][2];
#pragma unroll
        for (int i = 0; i < 4; ++i) {
            const int ra = wr * 64 + i * 16 + col;
            const int rb = wc * 64 + i * 16 + col;
#pragma unroll
            for (int kk = 0; kk < 2; ++kk) {
                a[i][kk] = *(const bf16x8*)&At[ra][(((kk << 2) + quad) ^ (ra & 7)) << 3];
                b[i][kk] = *(const bf16x8*)&Bt[rb][(((kk << 2) + quad) ^ (rb & 7)) << 3];
            }
        }
#pragma unroll
        for (int kk = 0; kk < 2; ++kk)
#pragma unroll
            for (int i = 0; i < 4; ++i)
#pragma unroll
                for (int j = 0; j < 4; ++j)
                    acc[i][j] = mfma16(a[i][kk], b[j][kk], acc[i][j]);
        __syncthreads();
    }

    for (int i = 0; i < 4; ++i) {
        const int mbase = mb + wr * 64 + i * 16 + quad * 4;
        const int bb = mbase >> 11, l = mbase & 2047;
        for (int j = 0; j < 4; ++j) {
            const int n = nb + wc * 64 + j * 16 + col;
            const float bv = bias ? bias[n] : 0.f;
            if (mode == 3) {
                float* o = (float*)dst;
                for (int r = 0; r < 4; ++r)
                    o[(size_t)(mbase + r) * 1024 + n] = clamp4(acc[i][j][r] + bv);
            } else if (mode == 2) {
                const int h = n >> 6, hd = n & 63;
                us4 pk;
                for (int r = 0; r < 4; ++r) pk[r] = f2bf(clamp4(acc[i][j][r] + bv));
                *(us4*)((unsigned short*)dst + (size_t)(bb * 16 + h) * 131072
                        + (size_t)hd * 2048 + l) = pk;
            } else {
                const int h = n >> 6, hd = n & 63;
                unsigned short* o = (unsigned short*)dst + (size_t)(bb * 16 + h) * 131072
                                    + (size_t)l * 64 + hd;
                for (int r = 0; r < 4; ++r)
                    o[(size_t)r * 64] = f2bf(clamp4(acc[i][j][r] + bv));
            }
        }
    }
}

// ---- attn32d: swapped-QK 32x32 in-register-softmax flash attention ----
// S^T acc layout (m74/m101): col q = lane&31; k = (reg&3) + 8*(reg>>2) + 4*hi.
// A-frag build (m214 recipe): pairs (r,r+1) cvt_pk'd, (r0..) swapped with (r4..)
// via v_permlane32_swap: first -> [lo,lo] word, second -> [hi,hi] word.
// (soft_pack / step math verbatim the R2-passing code.)

template<bool DIAG>
__device__ __forceinline__ void soft_pack(
    const f32x16& sacc, bf16x8* pa, float& lpart, int kg0, int qg)
{
    float p[16];
#pragma unroll
    for (int r = 0; r < 16; ++r) {
        float v = sacc[r] * 0.18033688f;   // 0.125 * log2(e): exp2 domain
        if (DIAG) {
            int kg = kg0 + (r & 3) + 8 * (r >> 2);
            if (kg > qg) v = -1e30f;
        }
        v = fminf(v, 86.5f);               // overflow guard (== e-domain 60)
        p[r] = EXP2F(v);
    }
    float t0 = (p[0] + p[1]) + (p[2] + p[3]);
    float t1 = (p[4] + p[5]) + (p[6] + p[7]);
    float t2 = (p[8] + p[9]) + (p[10] + p[11]);
    float t3 = (p[12] + p[13]) + (p[14] + p[15]);
    lpart += (t0 + t1) + (t2 + t3);
#pragma unroll
    for (int c = 0; c < 2; ++c) {
        unsigned int a0 = cvt_pk_bf16(p[8*c + 0], p[8*c + 1]);
        unsigned int b0 = cvt_pk_bf16(p[8*c + 4], p[8*c + 5]);
        unsigned int a1 = cvt_pk_bf16(p[8*c + 2], p[8*c + 3]);
        unsigned int b1 = cvt_pk_bf16(p[8*c + 6], p[8*c + 7]);
        pl32swap(a0, b0);                  // a0 -> w0 (lo:k01 / hi:k89), b0 -> w2
        pl32swap(a1, b1);                  // a1 -> w1,                  b1 -> w3
        union PW { unsigned int w[4]; bf16x8 v; } pw;
        pw.w[0] = a0; pw.w[1] = a1; pw.w[2] = b0; pw.w[3] = b1;
        pa[c] = pw.v;
    }
}

// One 64-k sub-tile step. Kt: 64-row sub-tile base (stride 72). Vt: pointer to
// &V_lds[0][col0], row stride 136 (64 hd rows x 128 k cols tile).
template<bool DIAG>
__device__ __forceinline__ void attn32_step2(
    const unsigned short (*__restrict__ Kt)[72], const unsigned short* __restrict__ Vt,
    const bf16x8* __restrict__ qf, f32x16* __restrict__ oacc, float& lpart,
    int kb, int qg, int hi, int c31)
{
    f32x16 s0, s1;
#pragma unroll
    for (int r = 0; r < 16; ++r) { s0[r] = 0.f; s1[r] = 0.f; }
#pragma unroll
    for (int dc = 0; dc < 4; ++dc) {
        bf16x8 kf0 = *(const bf16x8*)&Kt[c31][dc * 16 + hi * 8];
        bf16x8 kf1 = *(const bf16x8*)&Kt[32 + c31][dc * 16 + hi * 8];
        s0 = mfma32(kf0, qf[dc], s0);
        s1 = mfma32(kf1, qf[dc], s1);
    }
    bf16x8 pa[4];
    soft_pack<DIAG>(s0, pa,     lpart, kb + 4 * hi,      qg);
    soft_pack<DIAG>(s1, pa + 2, lpart, kb + 32 + 4 * hi, qg);
#pragma unroll
    for (int b2 = 0; b2 < 2; ++b2)
#pragma unroll
        for (int kc = 0; kc < 4; ++kc) {
            bf16x8 vf = *(const bf16x8*)&Vt[(size_t)(b2 * 32 + c31) * 136 + kc * 16 + hi * 8];
            oacc[b2] = mfma32(pa[kc], vf, oacc[b2]);
        }
}

__device__ __forceinline__ void attn_write32(
    unsigned short* __restrict__ mixed, int gb, int h, int q0, int c31, int hi,
    const f32x16* __restrict__ oacc, const float* __restrict__ lrow)
{
    f32x4 iv[4];
#pragma unroll
    for (int m = 0; m < 4; ++m) {
        f32x4 lv = *(const f32x4*)&lrow[4 * hi + 8 * m];
#pragma unroll
        for (int r = 0; r < 4; ++r) iv[m][r] = 1.f / lv[r];
    }
#pragma unroll
    for (int b2 = 0; b2 < 2; ++b2)
#pragma unroll
        for (int r = 0; r < 16; ++r) {
            const int qrow = q0 + 4 * hi + (r & 3) + 8 * (r >> 2);
            const float val = clamp4(oacc[b2][r] * iv[r >> 2][r & 3]);
            mixed[(size_t)(gb * 2048 + qrow) * 1024 + h * 64 + b2 * 32 + c31] = f2bf(val);
        }
}

// Wave = 32 q-rows, block = 4 waves = 128-row band A (0..15). KVBLK=128: each
// staged iteration jj covers 64-k sub-tiles t0=2jj, t1=2jj+1; band A runs A+1
// iterations. Diagonal: ss = 2A + (w>>1); on the last iteration sub-tile t==ss
// gets the mask, t>ss skipped. Pairs {A,15-A} co-reside via stride-256 XCD
// model. Grid 512 = {pair sel kk, bh, j}.
// Q,K: [bh][l][hd]; V: [bh][hd][l]; mixed: [4096][1024] bf16.
__global__ __launch_bounds__(256, 2) void attn32d(
    const unsigned short* __restrict__ Q, const unsigned short* __restrict__ K,
    const unsigned short* __restrict__ V, unsigned short* __restrict__ mixed)
{
    const int lb = blockIdx.x;
    const int i = lb & 255, kk = lb >> 8;
    const int bh = i & 31, j = i >> 5;        // j in [0,8)
    const int A = kk ? (15 - j) : j;          // 128-row band index 0..15
    const int niter = A + 1;                  // 128-wide k iterations

    const int tid = threadIdx.x, w = tid >> 6, lane = tid & 63;
    const int c31 = lane & 31, hi = lane >> 5;

    __shared__ __align__(16) unsigned short Kt[128][72];
    __shared__ __align__(16) unsigned short Vt[64][136];
    __shared__ __align__(16) float lslab[4][32];

    const unsigned short* Qb = Q + (size_t)bh * 131072;
    const unsigned short* Kb = K + (size_t)bh * 131072;
    const unsigned short* Vb = V + (size_t)bh * 131072;

    const int q0 = A * 128 + w * 32;
    const int qg = q0 + c31;                  // this lane's global q-row
    const int ss = 2 * A + (w >> 1);          // diagonal 64-sub-tile index

    bf16x8 qf[4];
    {
        const unsigned short* Qr = Qb + (size_t)qg * 64 + hi * 8;
#pragma unroll
        for (int dc = 0; dc < 4; ++dc) qf[dc] = *(const bf16x8*)(Qr + dc * 16);
    }

    f32x16 oacc[2];
#pragma unroll
    for (int b2 = 0; b2 < 2; ++b2)
#pragma unroll
        for (int r = 0; r < 16; ++r) oacc[b2][r] = 0.f;
    float lpart = 0.f;

    const int sr = tid >> 3, sc = (tid & 7) * 8;   // 32-row x 64-col write set

    // prefetch iteration 0: K rows 0..127 (4 sets), V cols 0..127 (2x2 sets)
    const unsigned short* kp = Kb + (size_t)sr * 64 + sc;
    const unsigned short* vp = Vb + (size_t)sr * 2048 + sc;
    bf16x8 pk0 = *(const bf16x8*)kp;
    bf16x8 pk1 = *(const bf16x8*)(kp + 32 * 64);
    bf16x8 pk2 = *(const bf16x8*)(kp + 64 * 64);
    bf16x8 pk3 = *(const bf16x8*)(kp + 96 * 64);
    bf16x8 pv0 = *(const bf16x8*)vp;
    bf16x8 pv1 = *(const bf16x8*)(vp + 32 * 2048);
    bf16x8 pv2 = *(const bf16x8*)(vp + 64);
    bf16x8 pv3 = *(const bf16x8*)(vp + 32 * 2048 + 64);

    for (int jj = 0; jj < niter; ++jj) {
        __syncthreads();                     // prior iter's LDS reads complete
        *(bf16x8*)&Kt[sr][sc]       = pk0;
        *(bf16x8*)&Kt[sr + 32][sc]  = pk1;
        *(bf16x8*)&Kt[sr + 64][sc]  = pk2;
        *(bf16x8*)&Kt[sr + 96][sc]  = pk3;
        *(bf16x8*)&Vt[sr][sc]       = pv0;
        *(bf16x8*)&Vt[sr + 32][sc]  = pv1;
        *(bf16x8*)&Vt[sr][64 + sc]  = pv2;
        *(bf16x8*)&Vt[sr + 32][64 + sc] = pv3;
        __syncthreads();
        if (jj + 1 < niter) {                // issue next iter's loads now:
            const int kb2 = (jj + 1) * 128;  // latency overlaps this iter's compute
            const unsigned short* kp2 = Kb + (size_t)(kb2 + sr) * 64 + sc;
            const unsigned short* vp2 = Vb + (size_t)sr * 2048 + kb2 + sc;
            pk0 = *(const bf16x8*)kp2;
            pk1 = *(const bf16x8*)(kp2 + 32 * 64);
            pk2 = *(const bf16x8*)(kp2 + 64 * 64);
            pk3 = *(const bf16x8*)(kp2 + 96 * 64);
            pv0 = *(const bf16x8*)vp2;
            pv1 = *(const bf16x8*)(vp2 + 32 * 2048);
            pv2 = *(const bf16x8*)(vp2 + 64);
            pv3 = *(const bf16x8*)(vp2 + 32 * 2048 + 64);
        }
        const int t0 = 2 * jj, t1 = t0 + 1;
        // sub-tile 0: K rows [0,64), V cols [0,64)
        if (t0 < ss)
            attn32_step2<false>(&Kt[0], &Vt[0][0],  qf, oacc, lpart, t0 * 64, qg, hi, c31);
        else if (t0 == ss)
            attn32_step2<true >(&Kt[0], &Vt[0][0],  qf, oacc, lpart, t0 * 64, qg, hi, c31);
        // sub-tile 1: K rows [64,128), V cols [64,128)
        if (t1 < ss)
            attn32_step2<false>(&Kt[64], &Vt[0][64], qf, oacc, lpart, t1 * 64, qg, hi, c31);
        else if (t1 == ss)
            attn32_step2<true >(&Kt[64], &Vt[0][64], qf, oacc, lpart, t1 * 64, qg, hi, c31);
        // t > ss: fully masked, skip (waves 0,1 on the last iteration)
    }

    // row-sum: combine lane-half partials, stash per-q, regather in reg-q order
    float ltot = lpart + __shfl_xor(lpart, 32, 64);
    if (lane < 32) lslab[w][lane] = ltot;    // q = lane (intra-wave ordered)

    const int gb = bh >> 4, h = bh & 15;
    attn_write32(mixed, gb, h, q0, c31, hi, oacc, &lslab[w][0]);
}

// ------------------------- fallback (round-3 proven) -------------------------

__device__ __forceinline__ bf16x8 load8(const void* base, size_t eoff, int asF32) {
    if (asF32) {
        const float* p = (const float*)base + eoff;
        f32x4 a = *(const f32x4*)p;
        f32x4 b = *(const f32x4*)(p + 4);
        U8 u;
        u.s[0]=f2bf(a[0]); u.s[1]=f2bf(a[1]); u.s[2]=f2bf(a[2]); u.s[3]=f2bf(a[3]);
        u.s[4]=f2bf(b[0]); u.s[5]=f2bf(b[1]); u.s[6]=f2bf(b[2]); u.s[7]=f2bf(b[3]);
        return u.v;
    }
    return *(const bf16x8*)((const unsigned short*)base + eoff);
}

__global__ void dtype_probe(const unsigned short* __restrict__ x, int* __restrict__ flag) {
    if (threadIdx.x == 0) {
        int c = 0;
        for (int i = 0; i < 128; ++i) {
            int e = (x[2 * i] >> 7) & 0xFF;
            if (e >= 100 && e <= 135) ++c;
        }
        *flag = (c < 64) ? 1 : 0;
    }
}

__global__ __launch_bounds__(256) void gemm_bt(
    const void* __restrict__ Ap, const void* __restrict__ Wp,
    const void* __restrict__ biasp, void* __restrict__ dout,
    unsigned short* __restrict__ wsdst, const int* __restrict__ flag,
    long aOff, long outOff, int mode, int aFlagged)
{
    const int f32 = *flag;
    __shared__ __align__(16) unsigned short At[64][32];
    __shared__ __align__(16) unsigned short Bt[64][32];
    const int mb = blockIdx.y * 64, nb = blockIdx.x * 64;
    const int tid = threadIdx.x;
    const int w = tid >> 6, lane = tid & 63;
    const int wr = w >> 1, wc = w & 1;
    const int col = lane & 15, quad = lane >> 4;
    const int srow = tid >> 2, schunk = (tid & 3) * 8;
    const int aF = aFlagged && f32;

    f32x4 acc[2][2];
    for (int i = 0; i < 2; ++i) for (int j = 0; j < 2; ++j) acc[i][j] = (f32x4){0.f,0.f,0.f,0.f};

    const size_t aBase = (size_t)aOff + (size_t)(mb + srow) * 1024 + schunk;
    const size_t wBase = (size_t)(nb + srow) * 1024 + schunk;

    for (int kb = 0; kb < 1024; kb += 32) {
        *(bf16x8*)(&At[srow][schunk]) = load8(Ap, aBase + kb, aF);
        *(bf16x8*)(&Bt[srow][schunk]) = load8(Wp, wBase + kb, f32);
        __syncthreads();
        bf16x8 a0 = *(const bf16x8*)(&At[wr * 32 + col][quad * 8]);
        bf16x8 a1 = *(const bf16x8*)(&At[wr * 32 + 16 + col][quad * 8]);
        bf16x8 b0 = *(const bf16x8*)(&Bt[wc * 32 + col][quad * 8]);
        bf16x8 b1 = *(const bf16x8*)(&Bt[wc * 32 + 16 + col][quad * 8]);
        acc[0][0] = mfma16(a0, b0, acc[0][0]);
        acc[0][1] = mfma16(a0, b1, acc[0][1]);
        acc[1][0] = mfma16(a1, b0, acc[1][0]);
        acc[1][1] = mfma16(a1, b1, acc[1][1]);
        __syncthreads();
    }

    for (int mi = 0; mi < 2; ++mi) {
        for (int ni = 0; ni < 2; ++ni) {
            int n = nb + wc * 32 + ni * 16 + col;
            float bv = 0.f;
            if (biasp) bv = f32 ? ((const float*)biasp)[n] : bf2f(((const unsigned short*)biasp)[n]);
            for (int r = 0; r < 4; ++r) {
                int m = mb + wr * 32 + mi * 16 + quad * 4 + r;
                float v = clamp4(acc[mi][ni][r] + bv);
                if (mode == 3) {
                    size_t idx = (size_t)outOff + (size_t)m * 1024 + n;
                    if (f32) ((float*)dout)[idx] = v;
                    else     ((unsigned short*)dout)[idx] = f2bf(v);
                } else {
                    int h = n >> 6, hd = n & 63;
                    size_t idx = (mode == 2)
                        ? (size_t)h * 131072 + (size_t)hd * 2048 + m
                        : (size_t)h * 131072 + (size_t)m * 64 + hd;
                    unsigned short* dstp = (mode == 0)
                        ? (unsigned short*)dout + (f32 ? 4194304 : 2097152)
                        : wsdst;
                    dstp[idx] = f2bf(v);
                }
            }
        }
    }
}

__global__ __launch_bounds__(256) void attn_kernel(
    const void* __restrict__ dout, const unsigned short* __restrict__ Kw,
    const unsigned short* __restrict__ Vw, unsigned short* __restrict__ mixed,
    const int* __restrict__ flag)
{
    const int f32 = *flag;
    const int qtile = blockIdx.x;
    const int h = blockIdx.y;
    const int w = threadIdx.x >> 6, lane = threadIdx.x & 63;
    const int col = lane & 15, quad = lane >> 4;

    __shared__ __align__(16) unsigned short Plds[4][16][64];

    const unsigned short* Qs = (const unsigned short*)dout + (f32 ? 4194304 : 2097152);
    const unsigned short* Qb = Qs + (size_t)h * 131072;
    const unsigned short* Kb = Kw + (size_t)h * 131072;
    const unsigned short* Vb = Vw + (size_t)h * 131072;

    const int q0 = qtile * 64 + w * 16;
    bf16x8 aq0 = *(const bf16x8*)(Qb + (size_t)(q0 + col) * 64 + quad * 8);
    bf16x8 aq1 = *(const bf16x8*)(Qb + (size_t)(q0 + col) * 64 + 32 + quad * 8);

    float m_run[4] = {-1e30f, -1e30f, -1e30f, -1e30f};
    float l_run[4] = {0.f, 0.f, 0.f, 0.f};
    f32x4 oacc[4];
    for (int i = 0; i < 4; ++i) oacc[i] = (f32x4){0.f, 0.f, 0.f, 0.f};

    for (int kt = 0; kt <= qtile; ++kt) {
        const int kb = kt * 64;
        f32x4 s[4];
        for (int t = 0; t < 4; ++t) {
            s[t] = (f32x4){0.f, 0.f, 0.f, 0.f};
            bf16x8 bk0 = *(const bf16x8*)(Kb + (size_t)(kb + t * 16 + col) * 64 + quad * 8);
            bf16x8 bk1 = *(const bf16x8*)(Kb + (size_t)(kb + t * 16 + col) * 64 + 32 + quad * 8);
            s[t] = mfma16(aq0, bk0, s[t]);
            s[t] = mfma16(aq1, bk1, s[t]);
        }
        for (int t = 0; t < 4; ++t)
            for (int r = 0; r < 4; ++r) {
                float v = clamp4(s[t][r] * 0.125f);
                if (kt == qtile && (t * 16 + col > w * 16 + quad * 4 + r)) v = -1e30f;
                s[t][r] = v;
            }
        float mt[4];
        for (int r = 0; r < 4; ++r)
            mt[r] = fmaxf(fmaxf(s[0][r], s[1][r]), fmaxf(s[2][r], s[3][r]));
        for (int off = 1; off < 16; off <<= 1)
            for (int r = 0; r < 4; ++r)
                mt[r] = fmaxf(mt[r], __shfl_xor(mt[r], off, 64));
        float alpha[4], rs[4], p[4][4];
        for (int r = 0; r < 4; ++r) {
            float mn = fmaxf(m_run[r], mt[r]);
            alpha[r] = __expf(m_run[r] - mn);
            m_run[r] = mn;
        }
        for (int t = 0; t < 4; ++t)
            for (int r = 0; r < 4; ++r)
                p[t][r] = __expf(s[t][r] - m_run[r]);
        for (int r = 0; r < 4; ++r)
            rs[r] = (p[0][r] + p[1][r]) + (p[2][r] + p[3][r]);
        for (int off = 1; off < 16; off <<= 1)
            for (int r = 0; r < 4; ++r)
                rs[r] += __shfl_xor(rs[r], off, 64);
        for (int r = 0; r < 4; ++r)
            l_run[r] = l_run[r] * alpha[r] + rs[r];
        for (int nt = 0; nt < 4; ++nt)
            for (int r = 0; r < 4; ++r)
                oacc[nt][r] *= alpha[r];
        for (int t = 0; t < 4; ++t)
            for (int r = 0; r < 4; ++r)
                Plds[w][quad * 4 + r][t * 16 + col] = f2bf(p[t][r]);
        __syncthreads();
        bf16x8 ap0 = *(const bf16x8*)(&Plds[w][col][quad * 8]);
        bf16x8 ap1 = *(const bf16x8*)(&Plds[w][col][32 + quad * 8]);
        for (int nt = 0; nt < 4; ++nt) {
            bf16x8 bv0 = *(const bf16x8*)(Vb + (size_t)(nt * 16 + col) * 2048 + kb + quad * 8);
            bf16x8 bv1 = *(const bf16x8*)(Vb + (size_t)(nt * 16 + col) * 2048 + kb + 32 + quad * 8);
            oacc[nt] = mfma16(ap0, bv0, oacc[nt]);
            oacc[nt] = mfma16(ap1, bv1, oacc[nt]);
        }
        __syncthreads();
    }

    float inv[4];
    for (int r = 0; r < 4; ++r) inv[r] = 1.f / l_run[r];
    for (int nt = 0; nt < 4; ++nt)
        for (int r = 0; r < 4; ++r) {
            int qrow = q0 + quad * 4 + r;
            mixed[(size_t)qrow * 1024 + h * 64 + nt * 16 + col] = f2bf(clamp4(oacc[nt][r] * inv[r]));
        }
}

// ------------------------- launcher -------------------------

extern "C" void kernel_launch(void* const* d_in, const int* in_sizes, int n_in,
                              void* d_out, int out_size, void* d_ws, size_t ws_size,
                              hipStream_t stream) {
    (void)in_sizes; (void)n_in; (void)out_size;
    const void* x  = d_in[0];
    const void* WQ = d_in[1]; const void* bQ = d_in[2];
    const void* WK = d_in[3]; const void* bK = d_in[4];
    const void* WV = d_in[5]; const void* bV = d_in[6];
    const void* Wc = d_in[7];

    if (ws_size >= (size_t)32 * 1024 * 1024) {
        unsigned short* wbf   = (unsigned short*)d_ws;      // 4M elems (8MB)
        unsigned short* Kst   = wbf + 4194304;
        unsigned short* VTst  = Kst + 4194304;
        unsigned short* mixed = VTst + 4194304;
        unsigned short* xbf   = (unsigned short*)d_out;     // d_out[0:8MB)
        unsigned short* Qst   = xbf + 4194304;              // d_out[8:16MB)

        convert_all<<<4096, 256, 0, stream>>>(
            (const float*)x, (const float*)WQ, (const float*)WK,
            (const float*)WV, (const float*)Wc, xbf, wbf);

        gemm128<<<dim3(8, 32, 3), 256, 0, stream>>>(
            xbf, wbf, (const float*)bQ, (const float*)bK, (const float*)bV,
            Qst, Kst, VTst, 0);

        attn32d<<<dim3(512, 1), 256, 0, stream>>>(Qst, Kst, VTst, mixed);

        gemm128<<<dim3(8, 32, 1), 256, 0, stream>>>(
            mixed, wbf + 3145728, nullptr, nullptr, nullptr,
            d_out, nullptr, nullptr, 3);
    } else {
        unsigned short* wsK = (unsigned short*)d_ws;
        unsigned short* wsV = wsK + 2097152;
        unsigned short* wsM = wsV + 2097152;
        int* flag = (int*)((char*)d_ws + 12 * 1024 * 1024);

        dtype_probe<<<1, 64, 0, stream>>>((const unsigned short*)x, flag);

        dim3 gg(16, 32), gb(256);
        for (int b = 0; b < 2; ++b) {
            long xo = (long)b * 2048 * 1024;
            gemm_bt<<<gg, gb, 0, stream>>>(x, WQ, bQ, d_out, nullptr, flag, xo, 0, 0, 1);
            gemm_bt<<<gg, gb, 0, stream>>>(x, WK, bK, d_out, wsK, flag, xo, 0, 1, 1);
            gemm_bt<<<gg, gb, 0, stream>>>(x, WV, bV, d_out, wsV, flag, xo, 0, 2, 1);
            attn_kernel<<<dim3(32, 16), 256, 0, stream>>>(d_out, wsK, wsV, wsM, flag);
            gemm_bt<<<gg, gb, 0, stream>>>(wsM, Wc, nullptr, d_out, nullptr, flag,
                                           0, (long)b * 2048 * 1024, 3, 0);
        }
    }
}